// Round 3
// baseline (665.484 us; speedup 1.0000x reference)
//
#include <hip/hip_runtime.h>
#include <hip/hip_bf16.h>

#define NODES 100000
#define EDGES 1600000
#define DIM   128

typedef __bf16 bf16x8 __attribute__((ext_vector_type(8)));
typedef __bf16 bf16x4 __attribute__((ext_vector_type(4)));
typedef float  f32x4  __attribute__((ext_vector_type(4)));

// global_load_lds: per-lane GLOBAL src, wave-uniform LDS base + lane*16 dest.
__device__ __forceinline__ void gather16(const float* gp, float* lp) {
    __builtin_amdgcn_global_load_lds(
        (const __attribute__((address_space(1))) void*)gp,
        (__attribute__((address_space(3))) void*)lp, 16, 0, 0);
}

// ================= edge-index dtype detection =================
__global__ void detect_kernel(const unsigned int* __restrict__ ei, int* __restrict__ flags) {
    const unsigned long long nz = __ballot(ei[2 * threadIdx.x + 1] != 0);
    if (threadIdx.x == 0) flags[0] = (nz == 0ULL) ? 1 : 0;
}

__device__ __forceinline__ int load_idx(const void* ei, long long pos, int m64) {
    return m64 ? (int)((const long long*)ei)[pos] : ((const int*)ei)[pos];
}

// ================= degree / normalization =================
__global__ __launch_bounds__(256) void zero_int_kernel(int* __restrict__ p, int n) {
    int i = blockIdx.x * 256 + threadIdx.x;
    if (i < n) p[i] = 0;
}

__global__ __launch_bounds__(256) void count_deg_kernel(const void* __restrict__ ei,
                                                        const int* __restrict__ flags,
                                                        int* __restrict__ deg, int e_cnt) {
    const int m64 = flags[0];
    int i = blockIdx.x * 256 + threadIdx.x;
    if (i < e_cnt) atomicAdd(&deg[load_idx(ei, (long long)EDGES + i, m64)], 1);
}

__global__ __launch_bounds__(256) void make_dis_kernel(const int* __restrict__ deg,
                                                       float* __restrict__ dis, int n) {
    int i = blockIdx.x * 256 + threadIdx.x;
    if (i < n) dis[i] = rsqrtf((float)deg[i] + 1.0f);
}

// ================= CSR build =================
__global__ __launch_bounds__(256) void scan1_kernel(const int* __restrict__ deg,
                                                    int* __restrict__ offs,
                                                    int* __restrict__ bsum, int n) {
    __shared__ int sm[256];
    const int t = threadIdx.x, i = blockIdx.x * 256 + t;
    const int v = (i < n) ? deg[i] : 0;
    sm[t] = v;
    __syncthreads();
    for (int d = 1; d < 256; d <<= 1) {
        const int add = (t >= d) ? sm[t - d] : 0;
        __syncthreads();
        sm[t] += add;
        __syncthreads();
    }
    if (i < n) offs[i] = sm[t] - v;
    if (t == 255) bsum[blockIdx.x] = sm[255];
}

__global__ __launch_bounds__(512) void scan2_kernel(const int* __restrict__ bsum,
                                                    int* __restrict__ boff,
                                                    int* __restrict__ offs, int nb, int n) {
    __shared__ int sm[512];
    const int t = threadIdx.x;
    const int v = (t < nb) ? bsum[t] : 0;
    sm[t] = v;
    __syncthreads();
    for (int d = 1; d < 512; d <<= 1) {
        const int add = (t >= d) ? sm[t - d] : 0;
        __syncthreads();
        sm[t] += add;
        __syncthreads();
    }
    if (t < nb) boff[t] = sm[t] - v;
    if (t == nb - 1) offs[n] = sm[t];
}

__global__ __launch_bounds__(256) void scan3_kernel(int* __restrict__ offs,
                                                    const int* __restrict__ boff,
                                                    int* __restrict__ cursor, int n) {
    const int i = blockIdx.x * 256 + threadIdx.x;
    if (i < n) {
        const int o = offs[i] + boff[blockIdx.x];
        offs[i]   = o;
        cursor[i] = o;
    }
}

__global__ __launch_bounds__(256) void fill_csr_kernel(const void* __restrict__ ei,
                                                       const int* __restrict__ flags,
                                                       const float* __restrict__ dis,
                                                       int* __restrict__ cursor,
                                                       int2* __restrict__ csr,
                                                       int e_cnt) {
    const int m64 = flags[0];
    int e = blockIdx.x * 256 + threadIdx.x;
    if (e >= e_cnt) return;
    const int s = load_idx(ei, e, m64);
    const int d = load_idx(ei, (long long)EDGES + e, m64);
    const int idx = atomicAdd(&cursor[d], 1);
    int2 rec;
    rec.x = s;
    rec.y = __float_as_int(dis[s] * dis[d]);
    csr[idx] = rec;
}

// ================= weight pre-pack: fp32 row-major -> bf16 MFMA fragment layout ==
// dest elem d: j=d&7, l15=(d>>3)&15, quad=(d>>7)&3, kt=(d>>9)&3, ct=(d>>11)&7
// value = (bf16) W[(kt*32+quad*8+j)*128 + ct*16 + l15]
// GEMM loads B as one coalesced bf16x8 (16B) per lane: Wf[(ct*4+kt)*512 + lane*8]
__global__ __launch_bounds__(256) void prep_w_kernel(
    const float* __restrict__ Wa, const float* __restrict__ Wb,
    const float* __restrict__ Wc, const float* __restrict__ Wd,
    __bf16* __restrict__ out)
{
    const int m = blockIdx.x >> 6;
    const int d = (blockIdx.x & 63) * 256 + threadIdx.x;
    const float* W = (m == 0) ? Wa : (m == 1) ? Wb : (m == 2) ? Wc : Wd;
    const int j  = d & 7;
    const int l  = (d >> 3) & 15;
    const int q  = (d >> 7) & 3;
    const int kt = (d >> 9) & 3;
    const int ct = (d >> 11) & 7;
    out[m * 16384 + d] = (__bf16)W[(kt * 32 + q * 8 + j) * DIM + ct * 16 + l];
}

// ================= GEMM: [M x 128] @ prepacked bf16 W -> fp32 =================
// 32 rows per wave (two 16-row tiles share every Wf fragment load).
// A/C-D fragment math identical to the verified kernel.
template <int RELU_BIAS, int ABF16>
__global__ __launch_bounds__(256) void gemm128_kernel(
    const void* __restrict__ Ain, const __bf16* __restrict__ Wf,
    const float* __restrict__ bias, float* __restrict__ out, int M)
{
    const int wave = threadIdx.x >> 6;
    const int lane = threadIdx.x & 63;
    const int l15  = lane & 15;
    const int quad = lane >> 4;

    const int row0 = blockIdx.x * 128 + wave * 32;
    if (row0 >= M) return;  // wave-uniform

    bf16x8 afA[4], afB[4];
#pragma unroll
    for (int t = 0; t < 2; t++) {
        const int arow  = row0 + t * 16 + l15;
        const int arowc = arow < M ? arow : (M - 1);
        bf16x8* af = t ? afB : afA;
        if (ABF16) {
            const __bf16* ap = (const __bf16*)Ain + (size_t)arowc * DIM + quad * 8;
#pragma unroll
            for (int kt = 0; kt < 4; kt++) af[kt] = *(const bf16x8*)(ap + kt * 32);
        } else {
            const float* ap = (const float*)Ain + (size_t)arowc * DIM + quad * 8;
#pragma unroll
            for (int kt = 0; kt < 4; kt++) {
                const f32x4 lo = *(const f32x4*)(ap + kt * 32);
                const f32x4 hi = *(const f32x4*)(ap + kt * 32 + 4);
                bf16x8 r;
#pragma unroll
                for (int j = 0; j < 4; j++) { r[j] = (__bf16)lo[j]; r[j + 4] = (__bf16)hi[j]; }
                af[kt] = r;
            }
        }
    }

#pragma unroll
    for (int ct = 0; ct < 8; ct++) {
        f32x4 cA = {0.f, 0.f, 0.f, 0.f};
        f32x4 cB = {0.f, 0.f, 0.f, 0.f};
#pragma unroll
        for (int kt = 0; kt < 4; kt++) {
            const bf16x8 b = *(const bf16x8*)(Wf + (ct * 4 + kt) * 512 + lane * 8);
            cA = __builtin_amdgcn_mfma_f32_16x16x32_bf16(afA[kt], b, cA, 0, 0, 0);
            cB = __builtin_amdgcn_mfma_f32_16x16x32_bf16(afB[kt], b, cB, 0, 0, 0);
        }
        const float bb = RELU_BIAS ? bias[ct * 16 + l15] : 0.f;
#pragma unroll
        for (int t = 0; t < 2; t++) {
            const f32x4 c = t ? cB : cA;
#pragma unroll
            for (int r = 0; r < 4; r++) {
                const int row = row0 + t * 16 + quad * 4 + r;
                if (row < M) {
                    float v = c[r];
                    if (RELU_BIAS) { v += bb; v = v > 0.f ? v : 0.f; }
                    out[(size_t)row * DIM + ct * 16 + l15] = v;
                }
            }
        }
    }
}

// Dual-weight head GEMM, 32 rows/wave: reads A once, writes relu(A@W1+b1), relu(A@W2+b2).
__global__ __launch_bounds__(256) void gemm128_dual_kernel(
    const float* __restrict__ A,
    const __bf16* __restrict__ Wf1, const float* __restrict__ b1,
    const __bf16* __restrict__ Wf2, const float* __restrict__ b2,
    float* __restrict__ out1, float* __restrict__ out2, int M)
{
    const int wave = threadIdx.x >> 6;
    const int lane = threadIdx.x & 63;
    const int l15  = lane & 15;
    const int quad = lane >> 4;

    const int row0 = blockIdx.x * 128 + wave * 32;
    if (row0 >= M) return;

    bf16x8 afA[4], afB[4];
#pragma unroll
    for (int t = 0; t < 2; t++) {
        const int arow  = row0 + t * 16 + l15;
        const int arowc = arow < M ? arow : (M - 1);
        const float* ap = A + (size_t)arowc * DIM + quad * 8;
        bf16x8* af = t ? afB : afA;
#pragma unroll
        for (int kt = 0; kt < 4; kt++) {
            const f32x4 lo = *(const f32x4*)(ap + kt * 32);
            const f32x4 hi = *(const f32x4*)(ap + kt * 32 + 4);
            bf16x8 r;
#pragma unroll
            for (int j = 0; j < 4; j++) { r[j] = (__bf16)lo[j]; r[j + 4] = (__bf16)hi[j]; }
            af[kt] = r;
        }
    }

#pragma unroll
    for (int ct = 0; ct < 8; ct++) {
        f32x4 cA1 = {0.f,0.f,0.f,0.f}, cA2 = {0.f,0.f,0.f,0.f};
        f32x4 cB1 = {0.f,0.f,0.f,0.f}, cB2 = {0.f,0.f,0.f,0.f};
#pragma unroll
        for (int kt = 0; kt < 4; kt++) {
            const bf16x8 w1 = *(const bf16x8*)(Wf1 + (ct * 4 + kt) * 512 + lane * 8);
            const bf16x8 w2 = *(const bf16x8*)(Wf2 + (ct * 4 + kt) * 512 + lane * 8);
            cA1 = __builtin_amdgcn_mfma_f32_16x16x32_bf16(afA[kt], w1, cA1, 0, 0, 0);
            cA2 = __builtin_amdgcn_mfma_f32_16x16x32_bf16(afA[kt], w2, cA2, 0, 0, 0);
            cB1 = __builtin_amdgcn_mfma_f32_16x16x32_bf16(afB[kt], w1, cB1, 0, 0, 0);
            cB2 = __builtin_amdgcn_mfma_f32_16x16x32_bf16(afB[kt], w2, cB2, 0, 0, 0);
        }
        const float bb1 = b1[ct * 16 + l15];
        const float bb2 = b2[ct * 16 + l15];
#pragma unroll
        for (int t = 0; t < 2; t++) {
            const f32x4 c1 = t ? cB1 : cA1;
            const f32x4 c2 = t ? cB2 : cA2;
#pragma unroll
            for (int r = 0; r < 4; r++) {
                const int row = row0 + t * 16 + quad * 4 + r;
                if (row < M) {
                    float v1 = c1[r] + bb1; v1 = v1 > 0.f ? v1 : 0.f;
                    float v2 = c2[r] + bb2; v2 = v2 > 0.f ? v2 : 0.f;
                    out1[(size_t)row * DIM + ct * 16 + l15] = v1;
                    out2[(size_t)row * DIM + ct * 16 + l15] = v2;
                }
            }
        }
    }
}

// ================= aggregate: depth-2 pipelined CSR gather via global_load_lds ====
// out[v] = act( dis[v]^2*xw[v] + sum_p coef[p]*xw[csr[p].src] + bias )
// One wave per node; wave-private double buffer (2 x 8 rows x 512B); NO barriers.
// Steady-state per batch b: [load rec b+2] [issue 4 gathers b+1] [vmcnt(5): batch b
// landed, 5 newest (4 gathers b+1 + rec b+2) stay in flight] [consume b].
// Consume mapping is the exact inverse of the gather-lds write (lane l reads
// bytes l*16 of the buffer) -> zero bank conflicts; rows split by lane-half
// parity, cols by lane&31; one f32x4 acc/lane + final shfl_xor(32).
template <int RELU, int WF32, int WBF16>
__global__ __launch_bounds__(256) void aggregate_kernel(
    const int* __restrict__ offs, const int2* __restrict__ csr,
    const float* __restrict__ dis, const float* __restrict__ xw,
    const float* __restrict__ bias, float* __restrict__ out_f32,
    __bf16* __restrict__ out_bf, int n)
{
    __shared__ float sbuf[4][2][8 * DIM];        // 32 KB / block
    const int wid  = threadIdx.x >> 6;
    const int v    = blockIdx.x * 4 + wid;       // grid exact: v < n
    const int lane = threadIdx.x & 63;
    const int half = lane >> 5;                  // row parity
    const int c32  = lane & 31;                  // 16B chunk index in a row
    const int lmod = lane & 7;

    const int beg = offs[v];
    const int deg = offs[v + 1] - beg;
    const int nb  = (deg + 7) >> 3;

    f32x4 acc = {0.f, 0.f, 0.f, 0.f};
    if (half == 0) {                             // self-loop term on lanes 0..31
        const float dv = dis[v];
        acc = (dv * dv) * *(const f32x4*)(xw + (size_t)v * DIM + c32 * 4);
    }

    float* bufs[2] = { &sbuf[wid][0][0], &sbuf[wid][1][0] };

    // ---- prologue: recs batch0 -> issue gathers batch0 -> recs batch1 ----
    int p0 = beg + lmod;                 p0 = p0 < EDGES ? p0 : EDGES - 1;
    int2 rec_cur = csr[p0];              // compiler waits vmcnt(0) before use: fine here
#pragma unroll
    for (int i = 0; i < 4; i++) {
        const int rs = __shfl(rec_cur.x, 2 * i + half);
        gather16(xw + (size_t)rs * DIM + c32 * 4, bufs[0] + i * 256);
    }
    __builtin_amdgcn_sched_barrier(0);
    int p1 = beg + 8 + lmod;             p1 = p1 < EDGES ? p1 : EDGES - 1;
    int2 rec_nxt = csr[p1];
    __builtin_amdgcn_sched_barrier(0);

    for (int b = 0; b < nb; ++b) {
        const int bufsel = b & 1;
        // (1) prefetch records for batch b+2 (issued FIRST so the compiler's
        //     auto-wait before its use is a counted vmcnt, not vmcnt(0))
        int p2 = beg + (b + 2) * 8 + lmod;  p2 = p2 < EDGES ? p2 : EDGES - 1;
        int2 rec_fetch = csr[p2];
        __builtin_amdgcn_sched_barrier(0);

        const bool more = (b + 1 < nb);
        if (more) {
            // (2) issue gathers for batch b+1 (unconditional count: srcs valid)
            float* nbuf = bufs[bufsel ^ 1];
#pragma unroll
            for (int i = 0; i < 4; i++) {
                const int rs = __shfl(rec_nxt.x, 2 * i + half);
                gather16(xw + (size_t)rs * DIM + c32 * 4, nbuf + i * 256);
            }
            __builtin_amdgcn_sched_barrier(0);
            // (3) batch b's 4 gathers landed; keep 4 new gathers + 1 rec in flight
            asm volatile("s_waitcnt vmcnt(5)" ::: "memory");
        } else {
            asm volatile("s_waitcnt vmcnt(1)" ::: "memory");  // only rec_fetch remains
        }
        __builtin_amdgcn_sched_barrier(0);

        // (4) consume batch b: lane reads bytes lane*16 per 1KB sweep (linear)
        const float* fbuf = bufs[bufsel];
        const int nr = deg - b * 8;              // >0; >=8 except tail
        const float cfy = __int_as_float(rec_cur.y);
#pragma unroll
        for (int k = 0; k < 4; k++) {
            const int r = 2 * k + half;
            const float cr = __shfl(cfy, r);     // outside guard: all lanes active
            if (r < nr) {
                const f32x4 xv = *(const f32x4*)(fbuf + r * DIM + c32 * 4);
                acc += cr * xv;
            }
        }
        rec_cur = rec_nxt;
        rec_nxt = rec_fetch;                     // compiler waits vmcnt(4) here: rec done
    }

    // combine the two half partials; lanes 0..31 then hold cols c32*4..+3
#pragma unroll
    for (int j = 0; j < 4; j++) acc[j] += __shfl_xor(acc[j], 32);

    if (half == 0) {
        const int cc = c32 * 4;
        acc[0] += bias[cc];     acc[1] += bias[cc + 1];
        acc[2] += bias[cc + 2]; acc[3] += bias[cc + 3];
        if (RELU) {
#pragma unroll
            for (int j = 0; j < 4; j++) acc[j] = acc[j] > 0.f ? acc[j] : 0.f;
        }
        if (WF32) *(f32x4*)(out_f32 + (size_t)v * DIM + cc) = acc;
        if (WBF16) {
            bf16x4 bv;
#pragma unroll
            for (int j = 0; j < 4; j++) bv[j] = (__bf16)acc[j];
            *(bf16x4*)(out_bf + (size_t)v * DIM + cc) = bv;
        }
    }
}

// ================= launcher =================
extern "C" void kernel_launch(void* const* d_in, const int* in_sizes, int n_in,
                              void* d_out, int out_size, void* d_ws, size_t ws_size,
                              hipStream_t stream)
{
    const int N = NODES, E = EDGES;
    const size_t ND = (size_t)N * DIM;

    const float* x  = (const float*)d_in[0];
    const void*  ei = d_in[1];
    const float* W1 = (const float*)d_in[2];
    const float* b1 = (const float*)d_in[3];
    const float* W2 = (const float*)d_in[4];
    const float* b2 = (const float*)d_in[5];
    const float* Wv = (const float*)d_in[6];
    const float* bv = (const float*)d_in[7];
    const float* Wt = (const float*)d_in[8];
    const float* bt = (const float*)d_in[9];

    // ws layout (~16.2 MB)
    char* w = (char*)d_ws;
    int*    flags  = (int*)(w);
    int*    deg    = (int*)(w + (1 << 10));
    float*  dis    = (float*)(w + (512 << 10));
    int*    offs   = (int*)(w + (1 << 20));
    int*    cursor = (int*)(w + 1572864);
    int*    bsum   = (int*)(w + 2097152);
    int*    boff   = (int*)(w + 2101248);
    int2*   csr    = (int2*)(w + 3145728);        // E x 8B
    __bf16* wf     = (__bf16*)(w + 16000000);     // 4 x 16384 bf16 = 128 KB
    __bf16* wf1 = wf, *wf2 = wf + 16384, *wfv = wf + 32768, *wft = wf + 49152;

    float* out   = (float*)d_out;
    float* slot0 = out;              // h (fp32, final)
    float* slot1 = out + ND;         // h1 (bf16, temp) -> vis (fp32, final)
    float* slot2 = out + 2 * ND;     // xw1/xw2 (fp32, temp) -> txt (fp32, final)
    __bf16* h1bf = (__bf16*)slot1;

    const int GN   = (N + 255) / 256;   // 391
    const int GE   = (E + 255) / 256;
    const int GM   = (N + 127) / 128;   // 782 (32 rows/wave)
    const int GAG  = (N + 3) / 4;       // 25000 (exact)

    detect_kernel<<<1, 64, 0, stream>>>((const unsigned int*)ei, flags);
    zero_int_kernel<<<GN, 256, 0, stream>>>(deg, N);
    count_deg_kernel<<<GE, 256, 0, stream>>>(ei, flags, deg, E);
    make_dis_kernel<<<GN, 256, 0, stream>>>(deg, dis, N);
    prep_w_kernel<<<256, 256, 0, stream>>>(W1, W2, Wv, Wt, wf);

    scan1_kernel<<<GN, 256, 0, stream>>>(deg, offs, bsum, N);
    scan2_kernel<<<1, 512, 0, stream>>>(bsum, boff, offs, GN, N);
    scan3_kernel<<<GN, 256, 0, stream>>>(offs, boff, cursor, N);
    fill_csr_kernel<<<GE, 256, 0, stream>>>(ei, flags, dis, cursor, csr, E);

    // ---- layer 1 ----  (h1 stored bf16-only: bit-identical to GEMM2's old cvt)
    gemm128_kernel<0, 0><<<GM, 256, 0, stream>>>(x, wf1, nullptr, slot2, N);
    aggregate_kernel<1, 0, 1><<<GAG, 256, 0, stream>>>(offs, csr, dis, slot2, b1,
                                                       nullptr, h1bf, N);

    // ---- layer 2 ----  (bf16-A GEMM)
    gemm128_kernel<0, 1><<<GM, 256, 0, stream>>>(h1bf, wf2, nullptr, slot2, N);
    aggregate_kernel<0, 1, 0><<<GAG, 256, 0, stream>>>(offs, csr, dis, slot2, b2,
                                                       slot0, nullptr, N);

    // ---- heads (fused: read h once) ----
    gemm128_dual_kernel<<<GM, 256, 0, stream>>>(slot0, wfv, bv, wft, bt, slot1, slot2, N);
}

// Round 4
// 543.288 us; speedup vs baseline: 1.2249x; 1.2249x over previous
//
#include <hip/hip_runtime.h>
#include <hip/hip_bf16.h>
#include <hip/hip_fp16.h>

#define NODES 100000
#define EDGES 1600000
#define DIM   128

typedef __bf16   bf16x8 __attribute__((ext_vector_type(8)));
typedef float    f32x4  __attribute__((ext_vector_type(4)));
typedef _Float16 f16x8  __attribute__((ext_vector_type(8)));

// global_load_lds: per-lane GLOBAL src, wave-uniform LDS base + lane*16 dest.
__device__ __forceinline__ void gather16(const void* gp, void* lp) {
    __builtin_amdgcn_global_load_lds(
        (const __attribute__((address_space(1))) void*)gp,
        (__attribute__((address_space(3))) void*)lp, 16, 0, 0);
}

// ================= edge-index dtype detection =================
__global__ void detect_kernel(const unsigned int* __restrict__ ei, int* __restrict__ flags) {
    const unsigned long long nz = __ballot(ei[2 * threadIdx.x + 1] != 0);
    if (threadIdx.x == 0) flags[0] = (nz == 0ULL) ? 1 : 0;
}

__device__ __forceinline__ int load_idx(const void* ei, long long pos, int m64) {
    return m64 ? (int)((const long long*)ei)[pos] : ((const int*)ei)[pos];
}

// ================= degree / normalization =================
__global__ __launch_bounds__(256) void zero_int_kernel(int* __restrict__ p, int n) {
    int i = blockIdx.x * 256 + threadIdx.x;
    if (i < n) p[i] = 0;
}

__global__ __launch_bounds__(256) void count_deg_kernel(const void* __restrict__ ei,
                                                        const int* __restrict__ flags,
                                                        int* __restrict__ deg, int e_cnt) {
    const int m64 = flags[0];
    int i = blockIdx.x * 256 + threadIdx.x;
    if (i < e_cnt) atomicAdd(&deg[load_idx(ei, (long long)EDGES + i, m64)], 1);
}

__global__ __launch_bounds__(256) void make_dis_kernel(const int* __restrict__ deg,
                                                       float* __restrict__ dis, int n) {
    int i = blockIdx.x * 256 + threadIdx.x;
    if (i < n) dis[i] = rsqrtf((float)deg[i] + 1.0f);
}

// ================= CSR build =================
__global__ __launch_bounds__(256) void scan1_kernel(const int* __restrict__ deg,
                                                    int* __restrict__ offs,
                                                    int* __restrict__ bsum, int n) {
    __shared__ int sm[256];
    const int t = threadIdx.x, i = blockIdx.x * 256 + t;
    const int v = (i < n) ? deg[i] : 0;
    sm[t] = v;
    __syncthreads();
    for (int d = 1; d < 256; d <<= 1) {
        const int add = (t >= d) ? sm[t - d] : 0;
        __syncthreads();
        sm[t] += add;
        __syncthreads();
    }
    if (i < n) offs[i] = sm[t] - v;
    if (t == 255) bsum[blockIdx.x] = sm[255];
}

__global__ __launch_bounds__(512) void scan2_kernel(const int* __restrict__ bsum,
                                                    int* __restrict__ boff,
                                                    int* __restrict__ offs, int nb, int n) {
    __shared__ int sm[512];
    const int t = threadIdx.x;
    const int v = (t < nb) ? bsum[t] : 0;
    sm[t] = v;
    __syncthreads();
    for (int d = 1; d < 512; d <<= 1) {
        const int add = (t >= d) ? sm[t - d] : 0;
        __syncthreads();
        sm[t] += add;
        __syncthreads();
    }
    if (t < nb) boff[t] = sm[t] - v;
    if (t == nb - 1) offs[n] = sm[t];
}

__global__ __launch_bounds__(256) void scan3_kernel(int* __restrict__ offs,
                                                    const int* __restrict__ boff,
                                                    int* __restrict__ cursor, int n) {
    const int i = blockIdx.x * 256 + threadIdx.x;
    if (i < n) {
        const int o = offs[i] + boff[blockIdx.x];
        offs[i]   = o;
        cursor[i] = o;
    }
}

__global__ __launch_bounds__(256) void fill_csr_kernel(const void* __restrict__ ei,
                                                       const int* __restrict__ flags,
                                                       const float* __restrict__ dis,
                                                       int* __restrict__ cursor,
                                                       int2* __restrict__ csr,
                                                       int e_cnt) {
    const int m64 = flags[0];
    int e = blockIdx.x * 256 + threadIdx.x;
    if (e >= e_cnt) return;
    const int s = load_idx(ei, e, m64);
    const int d = load_idx(ei, (long long)EDGES + e, m64);
    const int idx = atomicAdd(&cursor[d], 1);
    int2 rec;
    rec.x = s;
    rec.y = __float_as_int(dis[s] * dis[d]);
    csr[idx] = rec;
}

// ================= weight pre-pack: fp32 row-major -> bf16 MFMA fragment layout ==
// dest elem d: j=d&7, l15=(d>>3)&15, quad=(d>>7)&3, kt=(d>>9)&3, ct=(d>>11)&7
// value = (bf16) W[(kt*32+quad*8+j)*128 + ct*16 + l15]
// GEMM loads B as one coalesced bf16x8 (16B) per lane: Wf[(ct*4+kt)*512 + lane*8]
__global__ __launch_bounds__(256) void prep_w_kernel(
    const float* __restrict__ Wa, const float* __restrict__ Wb,
    const float* __restrict__ Wc, const float* __restrict__ Wd,
    __bf16* __restrict__ out)
{
    const int m = blockIdx.x >> 6;
    const int d = (blockIdx.x & 63) * 256 + threadIdx.x;
    const float* W = (m == 0) ? Wa : (m == 1) ? Wb : (m == 2) ? Wc : Wd;
    const int j  = d & 7;
    const int l  = (d >> 3) & 15;
    const int q  = (d >> 7) & 3;
    const int kt = (d >> 9) & 3;
    const int ct = (d >> 11) & 7;
    out[m * 16384 + d] = (__bf16)W[(kt * 32 + q * 8 + j) * DIM + ct * 16 + l];
}

// ================= GEMM: [M x 128] @ prepacked bf16 W =================
// 32 rows per wave (two 16-row tiles share every Wf fragment load).
// A/C-D fragment math identical to the verified kernel.
// ABF16: A is bf16.  OUTF16: store result as fp16 (feeds the gather kernel).
template <int RELU_BIAS, int ABF16, int OUTF16>
__global__ __launch_bounds__(256) void gemm128_kernel(
    const void* __restrict__ Ain, const __bf16* __restrict__ Wf,
    const float* __restrict__ bias, void* __restrict__ outp, int M)
{
    const int wave = threadIdx.x >> 6;
    const int lane = threadIdx.x & 63;
    const int l15  = lane & 15;
    const int quad = lane >> 4;

    const int row0 = blockIdx.x * 128 + wave * 32;
    if (row0 >= M) return;  // wave-uniform

    bf16x8 afA[4], afB[4];
#pragma unroll
    for (int t = 0; t < 2; t++) {
        const int arow  = row0 + t * 16 + l15;
        const int arowc = arow < M ? arow : (M - 1);
        bf16x8* af = t ? afB : afA;
        if (ABF16) {
            const __bf16* ap = (const __bf16*)Ain + (size_t)arowc * DIM + quad * 8;
#pragma unroll
            for (int kt = 0; kt < 4; kt++) af[kt] = *(const bf16x8*)(ap + kt * 32);
        } else {
            const float* ap = (const float*)Ain + (size_t)arowc * DIM + quad * 8;
#pragma unroll
            for (int kt = 0; kt < 4; kt++) {
                const f32x4 lo = *(const f32x4*)(ap + kt * 32);
                const f32x4 hi = *(const f32x4*)(ap + kt * 32 + 4);
                bf16x8 r;
#pragma unroll
                for (int j = 0; j < 4; j++) { r[j] = (__bf16)lo[j]; r[j + 4] = (__bf16)hi[j]; }
                af[kt] = r;
            }
        }
    }

#pragma unroll
    for (int ct = 0; ct < 8; ct++) {
        f32x4 cA = {0.f, 0.f, 0.f, 0.f};
        f32x4 cB = {0.f, 0.f, 0.f, 0.f};
#pragma unroll
        for (int kt = 0; kt < 4; kt++) {
            const bf16x8 b = *(const bf16x8*)(Wf + (ct * 4 + kt) * 512 + lane * 8);
            cA = __builtin_amdgcn_mfma_f32_16x16x32_bf16(afA[kt], b, cA, 0, 0, 0);
            cB = __builtin_amdgcn_mfma_f32_16x16x32_bf16(afB[kt], b, cB, 0, 0, 0);
        }
        const float bb = RELU_BIAS ? bias[ct * 16 + l15] : 0.f;
#pragma unroll
        for (int t = 0; t < 2; t++) {
            const f32x4 c = t ? cB : cA;
#pragma unroll
            for (int r = 0; r < 4; r++) {
                const int row = row0 + t * 16 + quad * 4 + r;
                if (row < M) {
                    float v = c[r];
                    if (RELU_BIAS) { v += bb; v = v > 0.f ? v : 0.f; }
                    const size_t idx = (size_t)row * DIM + ct * 16 + l15;
                    if (OUTF16) ((_Float16*)outp)[idx] = (_Float16)v;
                    else        ((float*)outp)[idx]    = v;
                }
            }
        }
    }
}

// Dual-weight head GEMM, 32 rows/wave: reads A once, writes relu(A@W1+b1), relu(A@W2+b2).
__global__ __launch_bounds__(256) void gemm128_dual_kernel(
    const float* __restrict__ A,
    const __bf16* __restrict__ Wf1, const float* __restrict__ b1,
    const __bf16* __restrict__ Wf2, const float* __restrict__ b2,
    float* __restrict__ out1, float* __restrict__ out2, int M)
{
    const int wave = threadIdx.x >> 6;
    const int lane = threadIdx.x & 63;
    const int l15  = lane & 15;
    const int quad = lane >> 4;

    const int row0 = blockIdx.x * 128 + wave * 32;
    if (row0 >= M) return;

    bf16x8 afA[4], afB[4];
#pragma unroll
    for (int t = 0; t < 2; t++) {
        const int arow  = row0 + t * 16 + l15;
        const int arowc = arow < M ? arow : (M - 1);
        const float* ap = A + (size_t)arowc * DIM + quad * 8;
        bf16x8* af = t ? afB : afA;
#pragma unroll
        for (int kt = 0; kt < 4; kt++) {
            const f32x4 lo = *(const f32x4*)(ap + kt * 32);
            const f32x4 hi = *(const f32x4*)(ap + kt * 32 + 4);
            bf16x8 r;
#pragma unroll
            for (int j = 0; j < 4; j++) { r[j] = (__bf16)lo[j]; r[j + 4] = (__bf16)hi[j]; }
            af[kt] = r;
        }
    }

#pragma unroll
    for (int ct = 0; ct < 8; ct++) {
        f32x4 cA1 = {0.f,0.f,0.f,0.f}, cA2 = {0.f,0.f,0.f,0.f};
        f32x4 cB1 = {0.f,0.f,0.f,0.f}, cB2 = {0.f,0.f,0.f,0.f};
#pragma unroll
        for (int kt = 0; kt < 4; kt++) {
            const bf16x8 w1 = *(const bf16x8*)(Wf1 + (ct * 4 + kt) * 512 + lane * 8);
            const bf16x8 w2 = *(const bf16x8*)(Wf2 + (ct * 4 + kt) * 512 + lane * 8);
            cA1 = __builtin_amdgcn_mfma_f32_16x16x32_bf16(afA[kt], w1, cA1, 0, 0, 0);
            cA2 = __builtin_amdgcn_mfma_f32_16x16x32_bf16(afA[kt], w2, cA2, 0, 0, 0);
            cB1 = __builtin_amdgcn_mfma_f32_16x16x32_bf16(afB[kt], w1, cB1, 0, 0, 0);
            cB2 = __builtin_amdgcn_mfma_f32_16x16x32_bf16(afB[kt], w2, cB2, 0, 0, 0);
        }
        const float bb1 = b1[ct * 16 + l15];
        const float bb2 = b2[ct * 16 + l15];
#pragma unroll
        for (int t = 0; t < 2; t++) {
            const f32x4 c1 = t ? cB1 : cA1;
            const f32x4 c2 = t ? cB2 : cA2;
#pragma unroll
            for (int r = 0; r < 4; r++) {
                const int row = row0 + t * 16 + quad * 4 + r;
                if (row < M) {
                    float v1 = c1[r] + bb1; v1 = v1 > 0.f ? v1 : 0.f;
                    float v2 = c2[r] + bb2; v2 = v2 > 0.f ? v2 : 0.f;
                    out1[(size_t)row * DIM + ct * 16 + l15] = v1;
                    out2[(size_t)row * DIM + ct * 16 + l15] = v2;
                }
            }
        }
    }
}

// ================= aggregate: depth-2 pipelined fp16 CSR gather =================
// out[v] = act( dis[v]^2*xw[v] + sum_p coef[p]*xw[csr[p].src] + bias )
// xw is fp16: a gathered row is 256B = 4 cache lines (was 8). The gather rate
// across R1-R3 was pinned at ~3.8 TB/s regardless of concurrency structure
// (per-CU L1 miss-path cap) -> halving lines/row is the remaining lever.
// One wave per node; wave-private double buffer 2 x (8 rows x 256B) = 4KB/wave
// (16KB/block -> occupancy back to R2's ~75%). Per batch of 8 edges only TWO
// global_load_lds dwordx4 (instr g covers rows 4g..4g+3; lane -> row lane>>4,
// halves (lane&15)*8). Depth-2: batch b+1's gathers + rec b+3 in flight while
// consuming b (vmcnt(3), FIFO retirement => batch b landed). Gathers are
// issued unconditionally with indices clamped to the node's last edge
// (stable vmcnt counts; junk is cache-hot and consume-guarded).
// Consume reads bytes lane*16 linearly -> zero bank conflicts.
template <int RELU, int WF32, int WBF16>
__global__ __launch_bounds__(256) void aggregate_kernel(
    const int* __restrict__ offs, const int2* __restrict__ csr,
    const float* __restrict__ dis, const _Float16* __restrict__ xw,
    const float* __restrict__ bias, float* __restrict__ out_f32,
    __bf16* __restrict__ out_bf, int n)
{
    __shared__ _Float16 sbuf[4][2][8 * DIM];     // 16 KB / block
    const int wid  = threadIdx.x >> 6;
    const int v    = blockIdx.x * 4 + wid;       // grid exact: v < n
    const int lane = threadIdx.x & 63;
    const int l15  = lane & 15;
    const int seg  = lane >> 4;                  // row-within-gather-instr
    const int lmod = lane & 7;

    const int beg = offs[v];
    const int deg = offs[v + 1] - beg;
    const int nb  = (deg + 7) >> 3;
    int lim = beg + deg - 1; if (lim < 0) lim = 0;   // clamp target (own last edge)

    _Float16* bufA = &sbuf[wid][0][0];
    _Float16* bufB = &sbuf[wid][1][0];

    f32x4 a0 = {0.f,0.f,0.f,0.f}, a1 = {0.f,0.f,0.f,0.f};
    if (seg == 0) {                              // self-loop term, one replica
        const float dv = dis[v];
        const float s2 = dv * dv;
        const f16x8 xv = *(const f16x8*)(xw + (size_t)v * DIM + l15 * 8);
#pragma unroll
        for (int j = 0; j < 4; j++) {
            a0[j] += s2 * (float)xv[j];
            a1[j] += s2 * (float)xv[j + 4];
        }
    }

    // rec loads on all lanes (8-way duplicated -> single 64B line)
    int p0 = beg + lmod;            p0 = p0 < lim ? p0 : lim;
    int2 rc = csr[p0];
#pragma unroll
    for (int g = 0; g < 2; g++) {                // issue gathers batch 0
        const int rs = __shfl(rc.x, g * 4 + seg);
        gather16(xw + (size_t)rs * DIM + l15 * 8, bufA + g * 512);
    }
    int p1 = beg + 8 + lmod;        p1 = p1 < lim ? p1 : lim;
    int2 rn1 = csr[p1];
    int p2 = beg + 16 + lmod;       p2 = p2 < lim ? p2 : lim;
    int2 rn2 = csr[p2];

    for (int b = 0; b < nb; ++b) {
        _Float16*       nbuf = (b & 1) ? bufA : bufB;
        const _Float16* cbuf = (b & 1) ? bufB : bufA;

        // issue gathers for batch b+1 (clamped; pure junk when b+1 == nb)
#pragma unroll
        for (int g = 0; g < 2; g++) {
            const int rs = __shfl(rn1.x, g * 4 + seg);
            gather16(xw + (size_t)rs * DIM + l15 * 8, nbuf + g * 512);
        }
        __builtin_amdgcn_sched_barrier(0);
        int p3 = beg + (b + 3) * 8 + lmod;  p3 = p3 < lim ? p3 : lim;
        int2 rn3 = csr[p3];
        __builtin_amdgcn_sched_barrier(0);
        // FIFO: allow {gathers b+1 (2), rec b+3 (1)} outstanding => batch b landed
        asm volatile("s_waitcnt vmcnt(3)" ::: "memory");
        __builtin_amdgcn_sched_barrier(0);

        const float cfy = __int_as_float(rc.y);
        const int rem = deg - b * 8;             // rows valid in this batch
#pragma unroll
        for (int s = 0; s < 2; s++) {
            const int r = s * 4 + seg;           // per-lane row 0..7
            const float cr = __shfl(cfy, r);
            if (r < rem) {                       // guard: junk/uninit LDS never touched
                const f16x8 hv = *(const f16x8*)(cbuf + s * 512 + lane * 8);
#pragma unroll
                for (int j = 0; j < 4; j++) {
                    a0[j] += cr * (float)hv[j];
                    a1[j] += cr * (float)hv[j + 4];
                }
            }
        }
        rc = rn1; rn1 = rn2; rn2 = rn3;
    }

    // reduce the 4 seg-partials; lanes 0..15 end up with cols l15*8..+7
#pragma unroll
    for (int j = 0; j < 4; j++) {
        a0[j] += __shfl_xor(a0[j], 16); a0[j] += __shfl_xor(a0[j], 32);
        a1[j] += __shfl_xor(a1[j], 16); a1[j] += __shfl_xor(a1[j], 32);
    }

    if (seg == 0) {
        const int cc = l15 * 8;
#pragma unroll
        for (int j = 0; j < 4; j++) { a0[j] += bias[cc + j]; a1[j] += bias[cc + 4 + j]; }
        if (RELU) {
#pragma unroll
            for (int j = 0; j < 4; j++) {
                a0[j] = a0[j] > 0.f ? a0[j] : 0.f;
                a1[j] = a1[j] > 0.f ? a1[j] : 0.f;
            }
        }
        if (WF32) {
            *(f32x4*)(out_f32 + (size_t)v * DIM + cc)     = a0;
            *(f32x4*)(out_f32 + (size_t)v * DIM + cc + 4) = a1;
        }
        if (WBF16) {
            bf16x8 bv;
#pragma unroll
            for (int j = 0; j < 4; j++) { bv[j] = (__bf16)a0[j]; bv[j + 4] = (__bf16)a1[j]; }
            *(bf16x8*)(out_bf + (size_t)v * DIM + cc) = bv;
        }
    }
    // drain stray clamped gathers before LDS dealloc at wave end
    asm volatile("s_waitcnt vmcnt(0)" ::: "memory");
}

// ================= launcher =================
extern "C" void kernel_launch(void* const* d_in, const int* in_sizes, int n_in,
                              void* d_out, int out_size, void* d_ws, size_t ws_size,
                              hipStream_t stream)
{
    const int N = NODES, E = EDGES;
    const size_t ND = (size_t)N * DIM;

    const float* x  = (const float*)d_in[0];
    const void*  ei = d_in[1];
    const float* W1 = (const float*)d_in[2];
    const float* b1 = (const float*)d_in[3];
    const float* W2 = (const float*)d_in[4];
    const float* b2 = (const float*)d_in[5];
    const float* Wv = (const float*)d_in[6];
    const float* bv = (const float*)d_in[7];
    const float* Wt = (const float*)d_in[8];
    const float* bt = (const float*)d_in[9];

    // ws layout (~16.2 MB)
    char* w = (char*)d_ws;
    int*    flags  = (int*)(w);
    int*    deg    = (int*)(w + (1 << 10));
    float*  dis    = (float*)(w + (512 << 10));
    int*    offs   = (int*)(w + (1 << 20));
    int*    cursor = (int*)(w + 1572864);
    int*    bsum   = (int*)(w + 2097152);
    int*    boff   = (int*)(w + 2101248);
    int2*   csr    = (int2*)(w + 3145728);        // E x 8B
    __bf16* wf     = (__bf16*)(w + 16000000);     // 4 x 16384 bf16 = 128 KB
    __bf16* wf1 = wf, *wf2 = wf + 16384, *wfv = wf + 32768, *wft = wf + 49152;

    float* out   = (float*)d_out;
    float* slot0 = out;              // h (fp32, final)
    float* slot1 = out + ND;         // h1 (bf16, temp) -> vis (fp32, final)
    float* slot2 = out + 2 * ND;     // xw1/xw2 (fp16, temp) -> txt (fp32, final)
    __bf16*   h1bf = (__bf16*)slot1;
    _Float16* xwh  = (_Float16*)slot2;

    const int GN   = (N + 255) / 256;   // 391
    const int GE   = (E + 255) / 256;
    const int GM   = (N + 127) / 128;   // 782 (32 rows/wave)
    const int GAG  = (N + 3) / 4;       // 25000 (exact)

    detect_kernel<<<1, 64, 0, stream>>>((const unsigned int*)ei, flags);
    zero_int_kernel<<<GN, 256, 0, stream>>>(deg, N);
    count_deg_kernel<<<GE, 256, 0, stream>>>(ei, flags, deg, E);
    make_dis_kernel<<<GN, 256, 0, stream>>>(deg, dis, N);
    prep_w_kernel<<<256, 256, 0, stream>>>(W1, W2, Wv, Wt, wf);

    scan1_kernel<<<GN, 256, 0, stream>>>(deg, offs, bsum, N);
    scan2_kernel<<<1, 512, 0, stream>>>(bsum, boff, offs, GN, N);
    scan3_kernel<<<GN, 256, 0, stream>>>(offs, boff, cursor, N);
    fill_csr_kernel<<<GE, 256, 0, stream>>>(ei, flags, dis, cursor, csr, E);

    // ---- layer 1 ----  (xw1 fp16; h1 bf16)
    gemm128_kernel<0, 0, 1><<<GM, 256, 0, stream>>>(x, wf1, nullptr, xwh, N);
    aggregate_kernel<1, 0, 1><<<GAG, 256, 0, stream>>>(offs, csr, dis, xwh, b1,
                                                       nullptr, h1bf, N);

    // ---- layer 2 ----  (bf16-A GEMM; xw2 fp16; h fp32 final)
    gemm128_kernel<0, 1, 1><<<GM, 256, 0, stream>>>(h1bf, wf2, nullptr, xwh, N);
    aggregate_kernel<0, 1, 0><<<GAG, 256, 0, stream>>>(offs, csr, dis, xwh, b2,
                                                       slot0, nullptr, N);

    // ---- heads (fused: read h once) ----
    gemm128_dual_kernel<<<GM, 256, 0, stream>>>(slot0, wfv, bv, wft, bt, slot1, slot2, N);
}

// Round 5
// 517.510 us; speedup vs baseline: 1.2859x; 1.0498x over previous
//
#include <hip/hip_runtime.h>
#include <hip/hip_bf16.h>
#include <hip/hip_fp16.h>

#define NODES 100000
#define EDGES 1600000
#define DIM   128

typedef __bf16   bf16x8 __attribute__((ext_vector_type(8)));
typedef float    f32x4  __attribute__((ext_vector_type(4)));
typedef _Float16 f16x8  __attribute__((ext_vector_type(8)));

// global_load_lds: per-lane GLOBAL src, wave-uniform LDS base + lane*16 dest.
__device__ __forceinline__ void gather16(const void* gp, void* lp) {
    __builtin_amdgcn_global_load_lds(
        (const __attribute__((address_space(1))) void*)gp,
        (__attribute__((address_space(3))) void*)lp, 16, 0, 0);
}

// ---- inline edge-index dtype detection (per wave; replaces detect_kernel) ----
// int64 indices < 2^31 => every odd dword zero. 64 random odd dwords all zero
// under int32: p ~ (1e-5)^64 ~ 0. L2-hot 256B read, 1 ballot.
__device__ __forceinline__ int wave_detect_m64(const void* ei) {
    const unsigned int* u = (const unsigned int*)ei;
    const unsigned long long nz = __ballot(u[2 * (threadIdx.x & 63) + 1] != 0);
    return (nz == 0ULL) ? 1 : 0;
}

__device__ __forceinline__ int load_idx(const void* ei, long long pos, int m64) {
    return m64 ? (int)((const long long*)ei)[pos] : ((const int*)ei)[pos];
}

// ================= init: zero deg (blocks [0,GN)) + weight pre-pack (blocks [GN,GN+256)) ==
// prep layout: dest elem d: j=d&7, l15=(d>>3)&15, quad=(d>>7)&3, kt=(d>>9)&3, ct=(d>>11)&7
// value = (bf16) W[(kt*32+quad*8+j)*128 + ct*16 + l15]
// GEMM loads B as one coalesced bf16x8 (16B) per lane: Wf[(ct*4+kt)*512 + lane*8]
__global__ __launch_bounds__(256) void init_kernel(
    int* __restrict__ deg, int n, int gn,
    const float* __restrict__ Wa, const float* __restrict__ Wb,
    const float* __restrict__ Wc, const float* __restrict__ Wd,
    __bf16* __restrict__ wfout)
{
    const int bid = blockIdx.x;
    if (bid < gn) {
        const int i = bid * 256 + threadIdx.x;
        if (i < n) deg[i] = 0;
    } else {
        const int pb = bid - gn;                       // 0..255
        const int m  = pb >> 6;
        const int d  = (pb & 63) * 256 + threadIdx.x;  // 0..16383
        const float* W = (m == 0) ? Wa : (m == 1) ? Wb : (m == 2) ? Wc : Wd;
        const int j  = d & 7;
        const int l  = (d >> 3) & 15;
        const int q  = (d >> 7) & 3;
        const int kt = (d >> 9) & 3;
        const int ct = (d >> 11) & 7;
        wfout[m * 16384 + d] = (__bf16)W[(kt * 32 + q * 8 + j) * DIM + ct * 16 + l];
    }
}

// ================= GEMM body: [M x 128] @ prepacked bf16 W =================
// 32 rows per wave (two 16-row tiles share every Wf fragment load).
// A/C-D fragment math identical to the verified kernel.
template <int RELU_BIAS, int ABF16, int OUTF16>
__device__ __forceinline__ void gemm_body(
    const void* __restrict__ Ain, const __bf16* __restrict__ Wf,
    const float* __restrict__ bias, void* __restrict__ outp, int M, int bid)
{
    const int wave = threadIdx.x >> 6;
    const int lane = threadIdx.x & 63;
    const int l15  = lane & 15;
    const int quad = lane >> 4;

    const int row0 = bid * 128 + wave * 32;
    if (row0 >= M) return;  // wave-uniform

    bf16x8 afA[4], afB[4];
#pragma unroll
    for (int t = 0; t < 2; t++) {
        const int arow  = row0 + t * 16 + l15;
        const int arowc = arow < M ? arow : (M - 1);
        bf16x8* af = t ? afB : afA;
        if (ABF16) {
            const __bf16* ap = (const __bf16*)Ain + (size_t)arowc * DIM + quad * 8;
#pragma unroll
            for (int kt = 0; kt < 4; kt++) af[kt] = *(const bf16x8*)(ap + kt * 32);
        } else {
            const float* ap = (const float*)Ain + (size_t)arowc * DIM + quad * 8;
#pragma unroll
            for (int kt = 0; kt < 4; kt++) {
                const f32x4 lo = *(const f32x4*)(ap + kt * 32);
                const f32x4 hi = *(const f32x4*)(ap + kt * 32 + 4);
                bf16x8 r;
#pragma unroll
                for (int j = 0; j < 4; j++) { r[j] = (__bf16)lo[j]; r[j + 4] = (__bf16)hi[j]; }
                af[kt] = r;
            }
        }
    }

#pragma unroll
    for (int ct = 0; ct < 8; ct++) {
        f32x4 cA = {0.f, 0.f, 0.f, 0.f};
        f32x4 cB = {0.f, 0.f, 0.f, 0.f};
#pragma unroll
        for (int kt = 0; kt < 4; kt++) {
            const bf16x8 b = *(const bf16x8*)(Wf + (ct * 4 + kt) * 512 + lane * 8);
            cA = __builtin_amdgcn_mfma_f32_16x16x32_bf16(afA[kt], b, cA, 0, 0, 0);
            cB = __builtin_amdgcn_mfma_f32_16x16x32_bf16(afB[kt], b, cB, 0, 0, 0);
        }
        const float bb = RELU_BIAS ? bias[ct * 16 + l15] : 0.f;
#pragma unroll
        for (int t = 0; t < 2; t++) {
            const f32x4 c = t ? cB : cA;
#pragma unroll
            for (int r = 0; r < 4; r++) {
                const int row = row0 + t * 16 + quad * 4 + r;
                if (row < M) {
                    float v = c[r];
                    if (RELU_BIAS) { v += bb; v = v > 0.f ? v : 0.f; }
                    const size_t idx = (size_t)row * DIM + ct * 16 + l15;
                    if (OUTF16) ((_Float16*)outp)[idx] = (_Float16)v;
                    else        ((float*)outp)[idx]    = v;
                }
            }
        }
    }
}

template <int RELU_BIAS, int ABF16, int OUTF16>
__global__ __launch_bounds__(256) void gemm128_kernel(
    const void* __restrict__ Ain, const __bf16* __restrict__ Wf,
    const float* __restrict__ bias, void* __restrict__ outp, int M)
{
    gemm_body<RELU_BIAS, ABF16, OUTF16>(Ain, Wf, bias, outp, M, blockIdx.x);
}

// ---- fused: gemm1 (x@W1 -> fp16) on blocks [0,GM) + count_deg on blocks [GM,GM+GE) ----
// The two are independent; fusing them co-schedules MFMA-heavy and atomic-heavy
// blocks instead of serializing two launches.
__global__ __launch_bounds__(256) void gemm1_count_kernel(
    const float* __restrict__ x, const __bf16* __restrict__ wf1,
    _Float16* __restrict__ xwh, int M, int gm,
    const void* __restrict__ ei, int* __restrict__ deg, int e_cnt)
{
    const int bid = blockIdx.x;
    if (bid < gm) {
        gemm_body<0, 0, 1>(x, wf1, nullptr, xwh, M, bid);
    } else {
        const int m64 = wave_detect_m64(ei);     // before any divergent exit
        const int i = (bid - gm) * 256 + threadIdx.x;
        if (i < e_cnt) atomicAdd(&deg[load_idx(ei, (long long)EDGES + i, m64)], 1);
    }
}

// Dual-weight head GEMM, 32 rows/wave: reads A once, writes relu(A@W1+b1), relu(A@W2+b2).
__global__ __launch_bounds__(256) void gemm128_dual_kernel(
    const float* __restrict__ A,
    const __bf16* __restrict__ Wf1, const float* __restrict__ b1,
    const __bf16* __restrict__ Wf2, const float* __restrict__ b2,
    float* __restrict__ out1, float* __restrict__ out2, int M)
{
    const int wave = threadIdx.x >> 6;
    const int lane = threadIdx.x & 63;
    const int l15  = lane & 15;
    const int quad = lane >> 4;

    const int row0 = blockIdx.x * 128 + wave * 32;
    if (row0 >= M) return;

    bf16x8 afA[4], afB[4];
#pragma unroll
    for (int t = 0; t < 2; t++) {
        const int arow  = row0 + t * 16 + l15;
        const int arowc = arow < M ? arow : (M - 1);
        const float* ap = A + (size_t)arowc * DIM + quad * 8;
        bf16x8* af = t ? afB : afA;
#pragma unroll
        for (int kt = 0; kt < 4; kt++) {
            const f32x4 lo = *(const f32x4*)(ap + kt * 32);
            const f32x4 hi = *(const f32x4*)(ap + kt * 32 + 4);
            bf16x8 r;
#pragma unroll
            for (int j = 0; j < 4; j++) { r[j] = (__bf16)lo[j]; r[j + 4] = (__bf16)hi[j]; }
            af[kt] = r;
        }
    }

#pragma unroll
    for (int ct = 0; ct < 8; ct++) {
        f32x4 cA1 = {0.f,0.f,0.f,0.f}, cA2 = {0.f,0.f,0.f,0.f};
        f32x4 cB1 = {0.f,0.f,0.f,0.f}, cB2 = {0.f,0.f,0.f,0.f};
#pragma unroll
        for (int kt = 0; kt < 4; kt++) {
            const bf16x8 w1 = *(const bf16x8*)(Wf1 + (ct * 4 + kt) * 512 + lane * 8);
            const bf16x8 w2 = *(const bf16x8*)(Wf2 + (ct * 4 + kt) * 512 + lane * 8);
            cA1 = __builtin_amdgcn_mfma_f32_16x16x32_bf16(afA[kt], w1, cA1, 0, 0, 0);
            cA2 = __builtin_amdgcn_mfma_f32_16x16x32_bf16(afA[kt], w2, cA2, 0, 0, 0);
            cB1 = __builtin_amdgcn_mfma_f32_16x16x32_bf16(afB[kt], w1, cB1, 0, 0, 0);
            cB2 = __builtin_amdgcn_mfma_f32_16x16x32_bf16(afB[kt], w2, cB2, 0, 0, 0);
        }
        const float bb1 = b1[ct * 16 + l15];
        const float bb2 = b2[ct * 16 + l15];
#pragma unroll
        for (int t = 0; t < 2; t++) {
            const f32x4 c1 = t ? cB1 : cA1;
            const f32x4 c2 = t ? cB2 : cA2;
#pragma unroll
            for (int r = 0; r < 4; r++) {
                const int row = row0 + t * 16 + quad * 4 + r;
                if (row < M) {
                    float v1 = c1[r] + bb1; v1 = v1 > 0.f ? v1 : 0.f;
                    float v2 = c2[r] + bb2; v2 = v2 > 0.f ? v2 : 0.f;
                    out1[(size_t)row * DIM + ct * 16 + l15] = v1;
                    out2[(size_t)row * DIM + ct * 16 + l15] = v2;
                }
            }
        }
    }
}

// ================= CSR build =================
// scan1: block-local exclusive scan of deg + dis = rsqrt(deg+1) (make_dis fused)
__global__ __launch_bounds__(256) void scan1_kernel(const int* __restrict__ deg,
                                                    int* __restrict__ offs,
                                                    int* __restrict__ bsum,
                                                    float* __restrict__ dis, int n) {
    __shared__ int sm[256];
    const int t = threadIdx.x, i = blockIdx.x * 256 + t;
    const int v = (i < n) ? deg[i] : 0;
    sm[t] = v;
    __syncthreads();
    for (int d = 1; d < 256; d <<= 1) {
        const int add = (t >= d) ? sm[t - d] : 0;
        __syncthreads();
        sm[t] += add;
        __syncthreads();
    }
    if (i < n) {
        offs[i] = sm[t] - v;
        dis[i]  = rsqrtf((float)v + 1.0f);
    }
    if (t == 255) bsum[blockIdx.x] = sm[255];
}

// scan23: each block computes its own boff = sum(bsum[j<bid]) (391 L2-hot ints),
// then applies it. offs[n] == EDGES statically.
__global__ __launch_bounds__(256) void scan23_kernel(int* __restrict__ offs,
                                                     const int* __restrict__ bsum,
                                                     int* __restrict__ cursor, int n) {
    __shared__ int sm[256];
    const int t = threadIdx.x, bid = blockIdx.x;
    int part = 0;
    for (int j = t; j < bid; j += 256) part += bsum[j];
    sm[t] = part;
    __syncthreads();
    for (int d = 128; d > 0; d >>= 1) {
        if (t < d) sm[t] += sm[t + d];
        __syncthreads();
    }
    const int boff = sm[0];
    const int i = bid * 256 + t;
    if (i < n) {
        const int o = offs[i] + boff;
        offs[i]   = o;
        cursor[i] = o;
    }
    if (bid == 0 && t == 0) offs[n] = EDGES;
}

__global__ __launch_bounds__(256) void fill_csr_kernel(const void* __restrict__ ei,
                                                       const float* __restrict__ dis,
                                                       int* __restrict__ cursor,
                                                       int2* __restrict__ csr,
                                                       int e_cnt) {
    const int m64 = wave_detect_m64(ei);         // before any divergent exit
    const int e = blockIdx.x * 256 + threadIdx.x;
    if (e >= e_cnt) return;
    const int s = load_idx(ei, e, m64);
    const int d = load_idx(ei, (long long)EDGES + e, m64);
    const int idx = atomicAdd(&cursor[d], 1);
    int2 rec;
    rec.x = s;
    rec.y = __float_as_int(dis[s] * dis[d]);
    csr[idx] = rec;
}

// ================= aggregate: depth-2 pipelined fp16 CSR gather =================
// out[v] = act( dis[v]^2*xw[v] + sum_p coef[p]*xw[csr[p].src] + bias )
// xw fp16: 256B/row = 4 cache lines. One wave per node; wave-private double
// buffer 2 x (8 rows x 256B) = 4KB/wave. Per batch of 8 edges two
// global_load_lds dwordx4 (instr g covers rows 4g..4g+3; lane -> row lane>>4,
// cols (lane&15)*8). Depth-2 FIFO (verified trace): while consuming batch b,
// gathers for b+1 + next recs are in flight; vmcnt(3) at the wait point
// guarantees batch b's gathers retired. Last batch: no junk issue, vmcnt(0).
// Consume reads bytes lane*16 linearly -> zero bank conflicts.
template <int RELU, int WF32, int WBF16>
__global__ __launch_bounds__(256) void aggregate_kernel(
    const int* __restrict__ offs, const int2* __restrict__ csr,
    const float* __restrict__ dis, const _Float16* __restrict__ xw,
    const float* __restrict__ bias, float* __restrict__ out_f32,
    __bf16* __restrict__ out_bf, int n)
{
    __shared__ _Float16 sbuf[4][2][8 * DIM];     // 16 KB / block
    const int wid  = threadIdx.x >> 6;
    const int v    = blockIdx.x * 4 + wid;       // grid exact: v < n
    const int lane = threadIdx.x & 63;
    const int l15  = lane & 15;
    const int seg  = lane >> 4;                  // row-within-gather-instr
    const int lmod = lane & 7;

    const int beg = offs[v];
    const int deg = offs[v + 1] - beg;
    const int nb  = (deg + 7) >> 3;
    int lim = beg + deg - 1; if (lim < 0) lim = 0;   // clamp target

    _Float16* bufA = &sbuf[wid][0][0];
    _Float16* bufB = &sbuf[wid][1][0];

    f32x4 a0 = {0.f,0.f,0.f,0.f}, a1 = {0.f,0.f,0.f,0.f};
    if (seg == 0) {                              // self-loop term, one replica
        const float dv = dis[v];
        const float s2 = dv * dv;
        const f16x8 xv = *(const f16x8*)(xw + (size_t)v * DIM + l15 * 8);
#pragma unroll
        for (int j = 0; j < 4; j++) {
            a0[j] += s2 * (float)xv[j];
            a1[j] += s2 * (float)xv[j + 4];
        }
    }

    // rec loads on all lanes (8-way duplicated -> single 64B line)
    int p0 = beg + lmod;            p0 = p0 < lim ? p0 : lim;
    int2 rc = csr[p0];
#pragma unroll
    for (int g = 0; g < 2; g++) {                // issue gathers batch 0
        const int rs = __shfl(rc.x, g * 4 + seg);
        gather16(xw + (size_t)rs * DIM + l15 * 8, bufA + g * 512);
    }
    int p1 = beg + 8 + lmod;        p1 = p1 < lim ? p1 : lim;
    int2 rn1 = csr[p1];
    int p2 = beg + 16 + lmod;       p2 = p2 < lim ? p2 : lim;
    int2 rn2 = csr[p2];

    for (int b = 0; b < nb; ++b) {
        _Float16*       nbuf = (b & 1) ? bufA : bufB;
        const _Float16* cbuf = (b & 1) ? bufB : bufA;
        const bool more = (b + 1 < nb);          // wave-uniform
        int2 rn3 = rn2;

        if (more) {
            // issue gathers for batch b+1 (real edges only)
#pragma unroll
            for (int g = 0; g < 2; g++) {
                const int rs = __shfl(rn1.x, g * 4 + seg);
                gather16(xw + (size_t)rs * DIM + l15 * 8, nbuf + g * 512);
            }
            __builtin_amdgcn_sched_barrier(0);
            int p3 = beg + (b + 3) * 8 + lmod;  p3 = p3 < lim ? p3 : lim;
            rn3 = csr[p3];
            __builtin_amdgcn_sched_barrier(0);
            // FIFO: {gathers b+1 (2), rec (1)} may stay in flight => batch b landed
            asm volatile("s_waitcnt vmcnt(3)" ::: "memory");
            __builtin_amdgcn_sched_barrier(0);
        } else {
            asm volatile("s_waitcnt vmcnt(0)" ::: "memory");
            __builtin_amdgcn_sched_barrier(0);
        }

        const float cfy = __int_as_float(rc.y);
        const int rem = deg - b * 8;             // rows valid in this batch
#pragma unroll
        for (int s = 0; s < 2; s++) {
            const int r = s * 4 + seg;           // per-lane row 0..7
            const float cr = __shfl(cfy, r);
            if (r < rem) {
                const f16x8 hv = *(const f16x8*)(cbuf + s * 512 + lane * 8);
#pragma unroll
                for (int j = 0; j < 4; j++) {
                    a0[j] += cr * (float)hv[j];
                    a1[j] += cr * (float)hv[j + 4];
                }
            }
        }
        rc = rn1; rn1 = rn2; rn2 = rn3;
    }

    // reduce the 4 seg-partials; lanes 0..15 end up with cols l15*8..+7
#pragma unroll
    for (int j = 0; j < 4; j++) {
        a0[j] += __shfl_xor(a0[j], 16); a0[j] += __shfl_xor(a0[j], 32);
        a1[j] += __shfl_xor(a1[j], 16); a1[j] += __shfl_xor(a1[j], 32);
    }

    if (seg == 0) {
        const int cc = l15 * 8;
#pragma unroll
        for (int j = 0; j < 4; j++) { a0[j] += bias[cc + j]; a1[j] += bias[cc + 4 + j]; }
        if (RELU) {
#pragma unroll
            for (int j = 0; j < 4; j++) {
                a0[j] = a0[j] > 0.f ? a0[j] : 0.f;
                a1[j] = a1[j] > 0.f ? a1[j] : 0.f;
            }
        }
        if (WF32) {
            *(f32x4*)(out_f32 + (size_t)v * DIM + cc)     = a0;
            *(f32x4*)(out_f32 + (size_t)v * DIM + cc + 4) = a1;
        }
        if (WBF16) {
            bf16x8 bv;
#pragma unroll
            for (int j = 0; j < 4; j++) { bv[j] = (__bf16)a0[j]; bv[j + 4] = (__bf16)a1[j]; }
            *(bf16x8*)(out_bf + (size_t)v * DIM + cc) = bv;
        }
    }
    // safety drain (nb==0 path still has prologue gathers in flight at exit)
    asm volatile("s_waitcnt vmcnt(0)" ::: "memory");
}

// ================= launcher =================
extern "C" void kernel_launch(void* const* d_in, const int* in_sizes, int n_in,
                              void* d_out, int out_size, void* d_ws, size_t ws_size,
                              hipStream_t stream)
{
    const int N = NODES, E = EDGES;
    const size_t ND = (size_t)N * DIM;

    const float* x  = (const float*)d_in[0];
    const void*  ei = d_in[1];
    const float* W1 = (const float*)d_in[2];
    const float* b1 = (const float*)d_in[3];
    const float* W2 = (const float*)d_in[4];
    const float* b2 = (const float*)d_in[5];
    const float* Wv = (const float*)d_in[6];
    const float* bv = (const float*)d_in[7];
    const float* Wt = (const float*)d_in[8];
    const float* bt = (const float*)d_in[9];

    // ws layout (~16.2 MB)
    char* w = (char*)d_ws;
    int*    deg    = (int*)(w + (1 << 10));
    float*  dis    = (float*)(w + (512 << 10));
    int*    offs   = (int*)(w + (1 << 20));
    int*    cursor = (int*)(w + 1572864);
    int*    bsum   = (int*)(w + 2097152);
    int2*   csr    = (int2*)(w + 3145728);        // E x 8B
    __bf16* wf     = (__bf16*)(w + 16000000);     // 4 x 16384 bf16 = 128 KB
    __bf16* wf1 = wf, *wf2 = wf + 16384, *wfv = wf + 32768, *wft = wf + 49152;

    float* out   = (float*)d_out;
    float* slot0 = out;              // h (fp32, final)
    float* slot1 = out + ND;         // h1 (bf16, temp) -> vis (fp32, final)
    float* slot2 = out + 2 * ND;     // xw1/xw2 (fp16, temp) -> txt (fp32, final)
    __bf16*   h1bf = (__bf16*)slot1;
    _Float16* xwh  = (_Float16*)slot2;

    const int GN   = (N + 255) / 256;   // 391
    const int GE   = (E + 255) / 256;   // 6250
    const int GM   = (N + 127) / 128;   // 782 (32 rows/wave)
    const int GAG  = (N + 3) / 4;       // 25000 (exact)

    // 1. zero deg + prep weights (independent halves)
    init_kernel<<<GN + 256, 256, 0, stream>>>(deg, N, GN, W1, W2, Wv, Wt, wf);
    // 2. gemm1 (independent) fused with count_deg -> co-scheduled
    gemm1_count_kernel<<<GM + GE, 256, 0, stream>>>(x, wf1, xwh, N, GM, ei, deg, E);
    // 3-4. scan (+dis), apply block offsets (+cursor); offs[N]=E static
    scan1_kernel<<<GN, 256, 0, stream>>>(deg, offs, bsum, dis, N);
    scan23_kernel<<<GN, 256, 0, stream>>>(offs, bsum, cursor, N);
    // 5. CSR fill
    fill_csr_kernel<<<GE, 256, 0, stream>>>(ei, dis, cursor, csr, E);

    // ---- layer 1 ----  (xw1 fp16 already done in step 2; h1 bf16)
    aggregate_kernel<1, 0, 1><<<GAG, 256, 0, stream>>>(offs, csr, dis, xwh, b1,
                                                       nullptr, h1bf, N);
    // ---- layer 2 ----  (bf16-A GEMM; xw2 fp16; h fp32 final)
    gemm128_kernel<0, 1, 1><<<GM, 256, 0, stream>>>(h1bf, wf2, nullptr, xwh, N);
    aggregate_kernel<0, 1, 0><<<GAG, 256, 0, stream>>>(offs, csr, dis, xwh, b2,
                                                       slot0, nullptr, N);
    // ---- heads (fused: read h once) ----
    gemm128_dual_kernel<<<GM, 256, 0, stream>>>(slot0, wfv, bv, wft, bt, slot1, slot2, N);
}

// Round 6
// 516.408 us; speedup vs baseline: 1.2887x; 1.0021x over previous
//
#include <hip/hip_runtime.h>
#include <hip/hip_bf16.h>
#include <hip/hip_fp16.h>

#define NODES 100000
#define EDGES 1600000
#define DIM   128

typedef __bf16   bf16x8 __attribute__((ext_vector_type(8)));
typedef float    f32x4  __attribute__((ext_vector_type(4)));
typedef _Float16 f16x8  __attribute__((ext_vector_type(8)));

// global_load_lds: per-lane GLOBAL src, wave-uniform LDS base + lane*16 dest.
__device__ __forceinline__ void gather16(const void* gp, void* lp) {
    __builtin_amdgcn_global_load_lds(
        (const __attribute__((address_space(1))) void*)gp,
        (__attribute__((address_space(3))) void*)lp, 16, 0, 0);
}

// ---- inline edge-index dtype detection (per wave) ----
// int64 indices < 2^31 => every odd dword zero. 64 random odd dwords all zero
// under int32: p ~ (1e-5)^64 ~ 0. L2-hot 256B read, 1 ballot.
__device__ __forceinline__ int wave_detect_m64(const void* ei) {
    const unsigned int* u = (const unsigned int*)ei;
    const unsigned long long nz = __ballot(u[2 * (threadIdx.x & 63) + 1] != 0);
    return (nz == 0ULL) ? 1 : 0;
}

__device__ __forceinline__ int load_idx(const void* ei, long long pos, int m64) {
    return m64 ? (int)((const long long*)ei)[pos] : ((const int*)ei)[pos];
}

// ================= init: zero padded counter region + weight pre-pack =================
// Counters are PADDED to one per 64B line (idx = d<<pshift, pshift=4): the 400KB
// compact array had 16 counters/line -> 256 device-scope atomics per line; same-line
// RMW serialization at the coherent point is the R5 theory for the ~95us idle-pipe
// atomic passes. Padding cuts it 16x.
// prep layout: dest elem d: j=d&7, l15=(d>>3)&15, quad=(d>>7)&3, kt=(d>>9)&3, ct=(d>>11)&7
// value = (bf16) W[(kt*32+quad*8+j)*128 + ct*16 + l15]
__global__ __launch_bounds__(256) void init_kernel(
    int* __restrict__ pad, int zcnt4, int zb,
    const float* __restrict__ Wa, const float* __restrict__ Wb,
    const float* __restrict__ Wc, const float* __restrict__ Wd,
    __bf16* __restrict__ wfout)
{
    const int bid = blockIdx.x;
    if (bid < zb) {
        const int i4 = bid * 256 + threadIdx.x;
        if (i4 < zcnt4) ((int4*)pad)[i4] = make_int4(0, 0, 0, 0);
    } else {
        const int pb = bid - zb;                       // 0..255
        const int m  = pb >> 6;
        const int d  = (pb & 63) * 256 + threadIdx.x;  // 0..16383
        const float* W = (m == 0) ? Wa : (m == 1) ? Wb : (m == 2) ? Wc : Wd;
        const int j  = d & 7;
        const int l  = (d >> 3) & 15;
        const int q  = (d >> 7) & 3;
        const int kt = (d >> 9) & 3;
        const int ct = (d >> 11) & 7;
        wfout[m * 16384 + d] = (__bf16)W[(kt * 32 + q * 8 + j) * DIM + ct * 16 + l];
    }
}

// ================= GEMM body: [M x 128] @ prepacked bf16 W =================
// 32 rows per wave (two 16-row tiles share every Wf fragment load).
// A/C-D fragment math identical to the verified kernel.
template <int RELU_BIAS, int ABF16, int OUTF16>
__device__ __forceinline__ void gemm_body(
    const void* __restrict__ Ain, const __bf16* __restrict__ Wf,
    const float* __restrict__ bias, void* __restrict__ outp, int M, int bid)
{
    const int wave = threadIdx.x >> 6;
    const int lane = threadIdx.x & 63;
    const int l15  = lane & 15;
    const int quad = lane >> 4;

    const int row0 = bid * 128 + wave * 32;
    if (row0 >= M) return;  // wave-uniform

    bf16x8 afA[4], afB[4];
#pragma unroll
    for (int t = 0; t < 2; t++) {
        const int arow  = row0 + t * 16 + l15;
        const int arowc = arow < M ? arow : (M - 1);
        bf16x8* af = t ? afB : afA;
        if (ABF16) {
            const __bf16* ap = (const __bf16*)Ain + (size_t)arowc * DIM + quad * 8;
#pragma unroll
            for (int kt = 0; kt < 4; kt++) af[kt] = *(const bf16x8*)(ap + kt * 32);
        } else {
            const float* ap = (const float*)Ain + (size_t)arowc * DIM + quad * 8;
#pragma unroll
            for (int kt = 0; kt < 4; kt++) {
                const f32x4 lo = *(const f32x4*)(ap + kt * 32);
                const f32x4 hi = *(const f32x4*)(ap + kt * 32 + 4);
                bf16x8 r;
#pragma unroll
                for (int j = 0; j < 4; j++) { r[j] = (__bf16)lo[j]; r[j + 4] = (__bf16)hi[j]; }
                af[kt] = r;
            }
        }
    }

#pragma unroll
    for (int ct = 0; ct < 8; ct++) {
        f32x4 cA = {0.f, 0.f, 0.f, 0.f};
        f32x4 cB = {0.f, 0.f, 0.f, 0.f};
#pragma unroll
        for (int kt = 0; kt < 4; kt++) {
            const bf16x8 b = *(const bf16x8*)(Wf + (ct * 4 + kt) * 512 + lane * 8);
            cA = __builtin_amdgcn_mfma_f32_16x16x32_bf16(afA[kt], b, cA, 0, 0, 0);
            cB = __builtin_amdgcn_mfma_f32_16x16x32_bf16(afB[kt], b, cB, 0, 0, 0);
        }
        const float bb = RELU_BIAS ? bias[ct * 16 + l15] : 0.f;
#pragma unroll
        for (int t = 0; t < 2; t++) {
            const f32x4 c = t ? cB : cA;
#pragma unroll
            for (int r = 0; r < 4; r++) {
                const int row = row0 + t * 16 + quad * 4 + r;
                if (row < M) {
                    float v = c[r];
                    if (RELU_BIAS) { v += bb; v = v > 0.f ? v : 0.f; }
                    const size_t idx = (size_t)row * DIM + ct * 16 + l15;
                    if (OUTF16) ((_Float16*)outp)[idx] = (_Float16)v;
                    else        ((float*)outp)[idx]    = v;
                }
            }
        }
    }
}

template <int RELU_BIAS, int ABF16, int OUTF16>
__global__ __launch_bounds__(256) void gemm128_kernel(
    const void* __restrict__ Ain, const __bf16* __restrict__ Wf,
    const float* __restrict__ bias, void* __restrict__ outp, int M)
{
    gemm_body<RELU_BIAS, ABF16, OUTF16>(Ain, Wf, bias, outp, M, blockIdx.x);
}

// ---- fused: gemm1 (x@W1 -> fp16) on blocks [0,GM) + count_deg on blocks [GM,GM+GE) ----
// count_deg atomics hit padded counters: pad[d << pshift].
__global__ __launch_bounds__(256) void gemm1_count_kernel(
    const float* __restrict__ x, const __bf16* __restrict__ wf1,
    _Float16* __restrict__ xwh, int M, int gm,
    const void* __restrict__ ei, int* __restrict__ pad, int pshift, int e_cnt)
{
    const int bid = blockIdx.x;
    if (bid < gm) {
        gemm_body<0, 0, 1>(x, wf1, nullptr, xwh, M, bid);
    } else {
        const int m64 = wave_detect_m64(ei);     // before any divergent exit
        const int i = (bid - gm) * 256 + threadIdx.x;
        if (i < e_cnt)
            atomicAdd(&pad[load_idx(ei, (long long)EDGES + i, m64) << pshift], 1);
    }
}

// Dual-weight head GEMM, 32 rows/wave: reads A once, writes relu(A@W1+b1), relu(A@W2+b2).
__global__ __launch_bounds__(256) void gemm128_dual_kernel(
    const float* __restrict__ A,
    const __bf16* __restrict__ Wf1, const float* __restrict__ b1,
    const __bf16* __restrict__ Wf2, const float* __restrict__ b2,
    float* __restrict__ out1, float* __restrict__ out2, int M)
{
    const int wave = threadIdx.x >> 6;
    const int lane = threadIdx.x & 63;
    const int l15  = lane & 15;
    const int quad = lane >> 4;

    const int row0 = blockIdx.x * 128 + wave * 32;
    if (row0 >= M) return;

    bf16x8 afA[4], afB[4];
#pragma unroll
    for (int t = 0; t < 2; t++) {
        const int arow  = row0 + t * 16 + l15;
        const int arowc = arow < M ? arow : (M - 1);
        const float* ap = A + (size_t)arowc * DIM + quad * 8;
        bf16x8* af = t ? afB : afA;
#pragma unroll
        for (int kt = 0; kt < 4; kt++) {
            const f32x4 lo = *(const f32x4*)(ap + kt * 32);
            const f32x4 hi = *(const f32x4*)(ap + kt * 32 + 4);
            bf16x8 r;
#pragma unroll
            for (int j = 0; j < 4; j++) { r[j] = (__bf16)lo[j]; r[j + 4] = (__bf16)hi[j]; }
            af[kt] = r;
        }
    }

#pragma unroll
    for (int ct = 0; ct < 8; ct++) {
        f32x4 cA1 = {0.f,0.f,0.f,0.f}, cA2 = {0.f,0.f,0.f,0.f};
        f32x4 cB1 = {0.f,0.f,0.f,0.f}, cB2 = {0.f,0.f,0.f,0.f};
#pragma unroll
        for (int kt = 0; kt < 4; kt++) {
            const bf16x8 w1 = *(const bf16x8*)(Wf1 + (ct * 4 + kt) * 512 + lane * 8);
            const bf16x8 w2 = *(const bf16x8*)(Wf2 + (ct * 4 + kt) * 512 + lane * 8);
            cA1 = __builtin_amdgcn_mfma_f32_16x16x32_bf16(afA[kt], w1, cA1, 0, 0, 0);
            cA2 = __builtin_amdgcn_mfma_f32_16x16x32_bf16(afA[kt], w2, cA2, 0, 0, 0);
            cB1 = __builtin_amdgcn_mfma_f32_16x16x32_bf16(afB[kt], w1, cB1, 0, 0, 0);
            cB2 = __builtin_amdgcn_mfma_f32_16x16x32_bf16(afB[kt], w2, cB2, 0, 0, 0);
        }
        const float bb1 = b1[ct * 16 + l15];
        const float bb2 = b2[ct * 16 + l15];
#pragma unroll
        for (int t = 0; t < 2; t++) {
            const f32x4 c1 = t ? cB1 : cA1;
            const f32x4 c2 = t ? cB2 : cA2;
#pragma unroll
            for (int r = 0; r < 4; r++) {
                const int row = row0 + t * 16 + quad * 4 + r;
                if (row < M) {
                    float v1 = c1[r] + bb1; v1 = v1 > 0.f ? v1 : 0.f;
                    float v2 = c2[r] + bb2; v2 = v2 > 0.f ? v2 : 0.f;
                    out1[(size_t)row * DIM + ct * 16 + l15] = v1;
                    out2[(size_t)row * DIM + ct * 16 + l15] = v2;
                }
            }
        }
    }
}

// ================= CSR build =================
// scan1: block-local exclusive scan of deg (strided reads from padded counters)
// + dis = rsqrt(deg+1)
__global__ __launch_bounds__(256) void scan1_kernel(const int* __restrict__ pad, int pshift,
                                                    int* __restrict__ offs,
                                                    int* __restrict__ bsum,
                                                    float* __restrict__ dis, int n) {
    __shared__ int sm[256];
    const int t = threadIdx.x, i = blockIdx.x * 256 + t;
    const int v = (i < n) ? pad[i << pshift] : 0;
    sm[t] = v;
    __syncthreads();
    for (int d = 1; d < 256; d <<= 1) {
        const int add = (t >= d) ? sm[t - d] : 0;
        __syncthreads();
        sm[t] += add;
        __syncthreads();
    }
    if (i < n) {
        offs[i] = sm[t] - v;
        dis[i]  = rsqrtf((float)v + 1.0f);
    }
    if (t == 255) bsum[blockIdx.x] = sm[255];
}

// scan23: each block computes its own boff = sum(bsum[j<bid]) (391 L2-hot ints),
// applies it to offs, and seeds the padded cursor array (aliases deg storage).
__global__ __launch_bounds__(256) void scan23_kernel(int* __restrict__ offs,
                                                     const int* __restrict__ bsum,
                                                     int* __restrict__ pad, int pshift, int n) {
    __shared__ int sm[256];
    const int t = threadIdx.x, bid = blockIdx.x;
    int part = 0;
    for (int j = t; j < bid; j += 256) part += bsum[j];
    sm[t] = part;
    __syncthreads();
    for (int d = 128; d > 0; d >>= 1) {
        if (t < d) sm[t] += sm[t + d];
        __syncthreads();
    }
    const int boff = sm[0];
    const int i = bid * 256 + t;
    if (i < n) {
        const int o = offs[i] + boff;
        offs[i]          = o;
        pad[i << pshift] = o;            // cursor (padded)
    }
    if (bid == 0 && t == 0) offs[n] = EDGES;
}

__global__ __launch_bounds__(256) void fill_csr_kernel(const void* __restrict__ ei,
                                                       const float* __restrict__ dis,
                                                       int* __restrict__ pad, int pshift,
                                                       int2* __restrict__ csr,
                                                       int e_cnt) {
    const int m64 = wave_detect_m64(ei);         // before any divergent exit
    const int e = blockIdx.x * 256 + threadIdx.x;
    if (e >= e_cnt) return;
    const int s = load_idx(ei, e, m64);
    const int d = load_idx(ei, (long long)EDGES + e, m64);
    const int idx = atomicAdd(&pad[d << pshift], 1);   // padded cursor: 16x less same-line RMW
    int2 rec;
    rec.x = s;
    rec.y = __float_as_int(dis[s] * dis[d]);
    csr[idx] = rec;
}

// ================= aggregate: depth-2 pipelined fp16 CSR gather =================
// out[v] = act( dis[v]^2*xw[v] + sum_p coef[p]*xw[csr[p].src] + bias )
// xw fp16: 256B/row = 4 cache lines. One wave per node; wave-private double
// buffer 2 x (8 rows x 256B) = 4KB/wave. Per batch of 8 edges two
// global_load_lds dwordx4 (instr g covers rows 4g..4g+3; lane -> row lane>>4,
// cols (lane&15)*8). Depth-2 FIFO: while consuming batch b, gathers for b+1 +
// next recs are in flight; vmcnt(3) at the wait point guarantees batch b's
// gathers retired. Last batch: vmcnt(0). Consume reads bytes lane*16 linearly
// -> zero bank conflicts. At ~6.2 TB/s serviced this kernel is at the per-CU
// line-request floor (R4 analysis).
template <int RELU, int WF32, int WBF16>
__global__ __launch_bounds__(256) void aggregate_kernel(
    const int* __restrict__ offs, const int2* __restrict__ csr,
    const float* __restrict__ dis, const _Float16* __restrict__ xw,
    const float* __restrict__ bias, float* __restrict__ out_f32,
    __bf16* __restrict__ out_bf, int n)
{
    __shared__ _Float16 sbuf[4][2][8 * DIM];     // 16 KB / block
    const int wid  = threadIdx.x >> 6;
    const int v    = blockIdx.x * 4 + wid;       // grid exact: v < n
    const int lane = threadIdx.x & 63;
    const int l15  = lane & 15;
    const int seg  = lane >> 4;                  // row-within-gather-instr
    const int lmod = lane & 7;

    const int beg = offs[v];
    const int deg = offs[v + 1] - beg;
    const int nb  = (deg + 7) >> 3;
    int lim = beg + deg - 1; if (lim < 0) lim = 0;   // clamp target

    _Float16* bufA = &sbuf[wid][0][0];
    _Float16* bufB = &sbuf[wid][1][0];

    f32x4 a0 = {0.f,0.f,0.f,0.f}, a1 = {0.f,0.f,0.f,0.f};
    if (seg == 0) {                              // self-loop term, one replica
        const float dv = dis[v];
        const float s2 = dv * dv;
        const f16x8 xv = *(const f16x8*)(xw + (size_t)v * DIM + l15 * 8);
#pragma unroll
        for (int j = 0; j < 4; j++) {
            a0[j] += s2 * (float)xv[j];
            a1[j] += s2 * (float)xv[j + 4];
        }
    }

    // rec loads on all lanes (8-way duplicated -> single 64B line)
    int p0 = beg + lmod;            p0 = p0 < lim ? p0 : lim;
    int2 rc = csr[p0];
#pragma unroll
    for (int g = 0; g < 2; g++) {                // issue gathers batch 0
        const int rs = __shfl(rc.x, g * 4 + seg);
        gather16(xw + (size_t)rs * DIM + l15 * 8, bufA + g * 512);
    }
    int p1 = beg + 8 + lmod;        p1 = p1 < lim ? p1 : lim;
    int2 rn1 = csr[p1];
    int p2 = beg + 16 + lmod;       p2 = p2 < lim ? p2 : lim;
    int2 rn2 = csr[p2];

    for (int b = 0; b < nb; ++b) {
        _Float16*       nbuf = (b & 1) ? bufA : bufB;
        const _Float16* cbuf = (b & 1) ? bufB : bufA;
        const bool more = (b + 1 < nb);          // wave-uniform
        int2 rn3 = rn2;

        if (more) {
            // issue gathers for batch b+1 (real edges only)
#pragma unroll
            for (int g = 0; g < 2; g++) {
                const int rs = __shfl(rn1.x, g * 4 + seg);
                gather16(xw + (size_t)rs * DIM + l15 * 8, nbuf + g * 512);
            }
            __builtin_amdgcn_sched_barrier(0);
            int p3 = beg + (b + 3) * 8 + lmod;  p3 = p3 < lim ? p3 : lim;
            rn3 = csr[p3];
            __builtin_amdgcn_sched_barrier(0);
            // FIFO: {gathers b+1 (2), rec (1)} may stay in flight => batch b landed
            asm volatile("s_waitcnt vmcnt(3)" ::: "memory");
            __builtin_amdgcn_sched_barrier(0);
        } else {
            asm volatile("s_waitcnt vmcnt(0)" ::: "memory");
            __builtin_amdgcn_sched_barrier(0);
        }

        const float cfy = __int_as_float(rc.y);
        const int rem = deg - b * 8;             // rows valid in this batch
#pragma unroll
        for (int s = 0; s < 2; s++) {
            const int r = s * 4 + seg;           // per-lane row 0..7
            const float cr = __shfl(cfy, r);
            if (r < rem) {
                const f16x8 hv = *(const f16x8*)(cbuf + s * 512 + lane * 8);
#pragma unroll
                for (int j = 0; j < 4; j++) {
                    a0[j] += cr * (float)hv[j];
                    a1[j] += cr * (float)hv[j + 4];
                }
            }
        }
        rc = rn1; rn1 = rn2; rn2 = rn3;
    }

    // reduce the 4 seg-partials; lanes 0..15 end up with cols l15*8..+7
#pragma unroll
    for (int j = 0; j < 4; j++) {
        a0[j] += __shfl_xor(a0[j], 16); a0[j] += __shfl_xor(a0[j], 32);
        a1[j] += __shfl_xor(a1[j], 16); a1[j] += __shfl_xor(a1[j], 32);
    }

    if (seg == 0) {
        const int cc = l15 * 8;
#pragma unroll
        for (int j = 0; j < 4; j++) { a0[j] += bias[cc + j]; a1[j] += bias[cc + 4 + j]; }
        if (RELU) {
#pragma unroll
            for (int j = 0; j < 4; j++) {
                a0[j] = a0[j] > 0.f ? a0[j] : 0.f;
                a1[j] = a1[j] > 0.f ? a1[j] : 0.f;
            }
        }
        if (WF32) {
            *(f32x4*)(out_f32 + (size_t)v * DIM + cc)     = a0;
            *(f32x4*)(out_f32 + (size_t)v * DIM + cc + 4) = a1;
        }
        if (WBF16) {
            bf16x8 bv;
#pragma unroll
            for (int j = 0; j < 4; j++) { bv[j] = (__bf16)a0[j]; bv[j + 4] = (__bf16)a1[j]; }
            *(bf16x8*)(out_bf + (size_t)v * DIM + cc) = bv;
        }
    }
    // safety drain (nb==0 path still has prologue gathers in flight at exit)
    asm volatile("s_waitcnt vmcnt(0)" ::: "memory");
}

// ================= launcher =================
extern "C" void kernel_launch(void* const* d_in, const int* in_sizes, int n_in,
                              void* d_out, int out_size, void* d_ws, size_t ws_size,
                              hipStream_t stream)
{
    const int N = NODES, E = EDGES;
    const size_t ND = (size_t)N * DIM;

    const float* x  = (const float*)d_in[0];
    const void*  ei = d_in[1];
    const float* W1 = (const float*)d_in[2];
    const float* b1 = (const float*)d_in[3];
    const float* W2 = (const float*)d_in[4];
    const float* b2 = (const float*)d_in[5];
    const float* Wv = (const float*)d_in[6];
    const float* bv = (const float*)d_in[7];
    const float* Wt = (const float*)d_in[8];
    const float* bt = (const float*)d_in[9];

    // ws layout: fixed small region + csr + wf, padded counters last (size flexes)
    char* w = (char*)d_ws;
    float*  dis   = (float*)(w + 4096);           // 400 KB
    int*    offs  = (int*)(w + (512 << 10));      // 400 KB + 4
    int*    bsum  = (int*)(w + (1 << 20));        // 1.6 KB
    int2*   csr   = (int2*)(w + 1310720);         // 12.8 MB, ends 14,110,720
    __bf16* wf    = (__bf16*)(w + 14155776);      // 128 KB, ends 14,286,848
    int*    pad   = (int*)(w + 14286848);         // counters: (N<<PSH)*4 bytes
    __bf16* wf1 = wf, *wf2 = wf + 16384, *wfv = wf + 32768, *wft = wf + 49152;

    // PSH=4 -> 1 counter / 64B line (6.4 MB, needs ws >= ~20.7MB);
    // PSH=2 -> 4 counters / line (1.6 MB fallback, fits the known-good 16.1MB).
    const int PSH = (ws_size >= 22u * 1024 * 1024) ? 4 : 2;

    float* out   = (float*)d_out;
    float* slot0 = out;              // h (fp32, final)
    float* slot1 = out + ND;         // h1 (bf16, temp) -> vis (fp32, final)
    float* slot2 = out + 2 * ND;     // xw1/xw2 (fp16, temp) -> txt (fp32, final)
    __bf16*   h1bf = (__bf16*)slot1;
    _Float16* xwh  = (_Float16*)slot2;

    const int GN   = (N + 255) / 256;   // 391
    const int GE   = (E + 255) / 256;   // 6250
    const int GM   = (N + 127) / 128;   // 782 (32 rows/wave)
    const int GAG  = (N + 3) / 4;       // 25000 (exact)

    const int zcnt4 = (N << PSH) >> 2;            // int4s to zero
    const int ZB    = (zcnt4 + 255) / 256;

    // 1. zero padded counters + prep weights (independent halves)
    init_kernel<<<ZB + 256, 256, 0, stream>>>(pad, zcnt4, ZB, W1, W2, Wv, Wt, wf);
    // 2. gemm1 (independent) fused with count_deg -> co-scheduled
    gemm1_count_kernel<<<GM + GE, 256, 0, stream>>>(x, wf1, xwh, N, GM, ei, pad, PSH, E);
    // 3-4. scan (+dis), apply block offsets (+padded cursor); offs[N]=E static
    scan1_kernel<<<GN, 256, 0, stream>>>(pad, PSH, offs, bsum, dis, N);
    scan23_kernel<<<GN, 256, 0, stream>>>(offs, bsum, pad, PSH, N);
    // 5. CSR fill (padded cursor atomics)
    fill_csr_kernel<<<GE, 256, 0, stream>>>(ei, dis, pad, PSH, csr, E);

    // ---- layer 1 ----  (xw1 fp16 already done in step 2; h1 bf16)
    aggregate_kernel<1, 0, 1><<<GAG, 256, 0, stream>>>(offs, csr, dis, xwh, b1,
                                                       nullptr, h1bf, N);
    // ---- layer 2 ----  (bf16-A GEMM; xw2 fp16; h fp32 final)
    gemm128_kernel<0, 1, 1><<<GM, 256, 0, stream>>>(h1bf, wf2, nullptr, xwh, N);
    aggregate_kernel<0, 1, 0><<<GAG, 256, 0, stream>>>(offs, csr, dis, xwh, b2,
                                                       slot0, nullptr, N);
    // ---- heads (fused: read h once) ----
    gemm128_dual_kernel<<<GM, 256, 0, stream>>>(slot0, wfv, bv, wft, bt, slot1, slot2, N);
}

// Round 8
// 487.228 us; speedup vs baseline: 1.3659x; 1.0599x over previous
//
#include <hip/hip_runtime.h>
#include <hip/hip_bf16.h>
#include <hip/hip_fp16.h>

#define NODES 100000
#define EDGES 1600000
#define DIM   128
#define NB    782      // dst buckets: node >> 7 (128 nodes/bucket)
#define KA    4096     // edges per phase-A block (32KB LDS stage -> total 45.5KB < 64KB)

typedef __bf16   bf16x8 __attribute__((ext_vector_type(8)));
typedef float    f32x4  __attribute__((ext_vector_type(4)));
typedef _Float16 f16x8  __attribute__((ext_vector_type(8)));

// global_load_lds: per-lane GLOBAL src, wave-uniform LDS base + lane*16 dest.
__device__ __forceinline__ void gather16(const void* gp, void* lp) {
    __builtin_amdgcn_global_load_lds(
        (const __attribute__((address_space(1))) void*)gp,
        (__attribute__((address_space(3))) void*)lp, 16, 0, 0);
}

// ---- inline edge-index dtype detection (per wave) ----
// int64 indices < 2^31 => every odd dword zero. 64 random odd dwords all zero
// under int32: p ~ 0. L2-hot 256B read, 1 ballot.
__device__ __forceinline__ int wave_detect_m64(const void* ei) {
    const unsigned int* u = (const unsigned int*)ei;
    const unsigned long long nz = __ballot(u[2 * (threadIdx.x & 63) + 1] != 0);
    return (nz == 0ULL) ? 1 : 0;
}

__device__ __forceinline__ int load_idx(const void* ei, long long pos, int m64) {
    return m64 ? (int)((const long long*)ei)[pos] : ((const int*)ei)[pos];
}

// ================= init: zero deg + weight pre-pack =================
// prep layout: dest elem d: j=d&7, l15=(d>>3)&15, quad=(d>>7)&3, kt=(d>>9)&3, ct=(d>>11)&7
// value = (bf16) W[(kt*32+quad*8+j)*128 + ct*16 + l15]
__global__ __launch_bounds__(256) void init_kernel(
    int* __restrict__ deg, int zcnt4, int zb,
    const float* __restrict__ Wa, const float* __restrict__ Wb,
    const float* __restrict__ Wc, const float* __restrict__ Wd,
    __bf16* __restrict__ wfout)
{
    const int bid = blockIdx.x;
    if (bid < zb) {
        const int i4 = bid * 256 + threadIdx.x;
        if (i4 < zcnt4) ((int4*)deg)[i4] = make_int4(0, 0, 0, 0);
    } else {
        const int pb = bid - zb;                       // 0..255
        const int m  = pb >> 6;
        const int d  = (pb & 63) * 256 + threadIdx.x;  // 0..16383
        const float* W = (m == 0) ? Wa : (m == 1) ? Wb : (m == 2) ? Wc : Wd;
        const int j  = d & 7;
        const int l  = (d >> 3) & 15;
        const int q  = (d >> 7) & 3;
        const int kt = (d >> 9) & 3;
        const int ct = (d >> 11) & 7;
        wfout[m * 16384 + d] = (__bf16)W[(kt * 32 + q * 8 + j) * DIM + ct * 16 + l];
    }
}

// ================= GEMM body: [M x 128] @ prepacked bf16 W =================
// 32 rows per wave (two 16-row tiles share every Wf fragment load).
template <int RELU_BIAS, int ABF16, int OUTF16>
__device__ __forceinline__ void gemm_body(
    const void* __restrict__ Ain, const __bf16* __restrict__ Wf,
    const float* __restrict__ bias, void* __restrict__ outp, int M, int bid)
{
    const int wave = threadIdx.x >> 6;
    const int lane = threadIdx.x & 63;
    const int l15  = lane & 15;
    const int quad = lane >> 4;

    const int row0 = bid * 128 + wave * 32;
    if (row0 >= M) return;  // wave-uniform

    bf16x8 afA[4], afB[4];
#pragma unroll
    for (int t = 0; t < 2; t++) {
        const int arow  = row0 + t * 16 + l15;
        const int arowc = arow < M ? arow : (M - 1);
        bf16x8* af = t ? afB : afA;
        if (ABF16) {
            const __bf16* ap = (const __bf16*)Ain + (size_t)arowc * DIM + quad * 8;
#pragma unroll
            for (int kt = 0; kt < 4; kt++) af[kt] = *(const bf16x8*)(ap + kt * 32);
        } else {
            const float* ap = (const float*)Ain + (size_t)arowc * DIM + quad * 8;
#pragma unroll
            for (int kt = 0; kt < 4; kt++) {
                const f32x4 lo = *(const f32x4*)(ap + kt * 32);
                const f32x4 hi = *(const f32x4*)(ap + kt * 32 + 4);
                bf16x8 r;
#pragma unroll
                for (int j = 0; j < 4; j++) { r[j] = (__bf16)lo[j]; r[j + 4] = (__bf16)hi[j]; }
                af[kt] = r;
            }
        }
    }

#pragma unroll
    for (int ct = 0; ct < 8; ct++) {
        f32x4 cA = {0.f, 0.f, 0.f, 0.f};
        f32x4 cB = {0.f, 0.f, 0.f, 0.f};
#pragma unroll
        for (int kt = 0; kt < 4; kt++) {
            const bf16x8 b = *(const bf16x8*)(Wf + (ct * 4 + kt) * 512 + lane * 8);
            cA = __builtin_amdgcn_mfma_f32_16x16x32_bf16(afA[kt], b, cA, 0, 0, 0);
            cB = __builtin_amdgcn_mfma_f32_16x16x32_bf16(afB[kt], b, cB, 0, 0, 0);
        }
        const float bb = RELU_BIAS ? bias[ct * 16 + l15] : 0.f;
#pragma unroll
        for (int t = 0; t < 2; t++) {
            const f32x4 c = t ? cB : cA;
#pragma unroll
            for (int r = 0; r < 4; r++) {
                const int row = row0 + t * 16 + quad * 4 + r;
                if (row < M) {
                    float v = c[r];
                    if (RELU_BIAS) { v += bb; v = v > 0.f ? v : 0.f; }
                    const size_t idx = (size_t)row * DIM + ct * 16 + l15;
                    if (OUTF16) ((_Float16*)outp)[idx] = (_Float16)v;
                    else        ((float*)outp)[idx]    = v;
                }
            }
        }
    }
}

template <int RELU_BIAS, int ABF16, int OUTF16>
__global__ __launch_bounds__(256) void gemm128_kernel(
    const void* __restrict__ Ain, const __bf16* __restrict__ Wf,
    const float* __restrict__ bias, void* __restrict__ outp, int M)
{
    gemm_body<RELU_BIAS, ABF16, OUTF16>(Ain, Wf, bias, outp, M, blockIdx.x);
}

// ---- fused: gemm1 (x@W1 -> fp16) on blocks [0,GM) + count_deg on blocks [GM,GM+GE) ----
__global__ __launch_bounds__(256) void gemm1_count_kernel(
    const float* __restrict__ x, const __bf16* __restrict__ wf1,
    _Float16* __restrict__ xwh, int M, int gm,
    const void* __restrict__ ei, int* __restrict__ deg, int e_cnt)
{
    const int bid = blockIdx.x;
    if (bid < gm) {
        gemm_body<0, 0, 1>(x, wf1, nullptr, xwh, M, bid);
    } else {
        const int m64 = wave_detect_m64(ei);     // before any divergent exit
        const int i = (bid - gm) * 256 + threadIdx.x;
        if (i < e_cnt)
            atomicAdd(&deg[load_idx(ei, (long long)EDGES + i, m64)], 1);
    }
}

// Dual-weight head GEMM, 32 rows/wave.
__global__ __launch_bounds__(256) void gemm128_dual_kernel(
    const float* __restrict__ A,
    const __bf16* __restrict__ Wf1, const float* __restrict__ b1,
    const __bf16* __restrict__ Wf2, const float* __restrict__ b2,
    float* __restrict__ out1, float* __restrict__ out2, int M)
{
    const int wave = threadIdx.x >> 6;
    const int lane = threadIdx.x & 63;
    const int l15  = lane & 15;
    const int quad = lane >> 4;

    const int row0 = blockIdx.x * 128 + wave * 32;
    if (row0 >= M) return;

    bf16x8 afA[4], afB[4];
#pragma unroll
    for (int t = 0; t < 2; t++) {
        const int arow  = row0 + t * 16 + l15;
        const int arowc = arow < M ? arow : (M - 1);
        const float* ap = A + (size_t)arowc * DIM + quad * 8;
        bf16x8* af = t ? afB : afA;
#pragma unroll
        for (int kt = 0; kt < 4; kt++) {
            const f32x4 lo = *(const f32x4*)(ap + kt * 32);
            const f32x4 hi = *(const f32x4*)(ap + kt * 32 + 4);
            bf16x8 r;
#pragma unroll
            for (int j = 0; j < 4; j++) { r[j] = (__bf16)lo[j]; r[j + 4] = (__bf16)hi[j]; }
            af[kt] = r;
        }
    }

#pragma unroll
    for (int ct = 0; ct < 8; ct++) {
        f32x4 cA1 = {0.f,0.f,0.f,0.f}, cA2 = {0.f,0.f,0.f,0.f};
        f32x4 cB1 = {0.f,0.f,0.f,0.f}, cB2 = {0.f,0.f,0.f,0.f};
#pragma unroll
        for (int kt = 0; kt < 4; kt++) {
            const bf16x8 w1 = *(const bf16x8*)(Wf1 + (ct * 4 + kt) * 512 + lane * 8);
            const bf16x8 w2 = *(const bf16x8*)(Wf2 + (ct * 4 + kt) * 512 + lane * 8);
            cA1 = __builtin_amdgcn_mfma_f32_16x16x32_bf16(afA[kt], w1, cA1, 0, 0, 0);
            cA2 = __builtin_amdgcn_mfma_f32_16x16x32_bf16(afA[kt], w2, cA2, 0, 0, 0);
            cB1 = __builtin_amdgcn_mfma_f32_16x16x32_bf16(afB[kt], w1, cB1, 0, 0, 0);
            cB2 = __builtin_amdgcn_mfma_f32_16x16x32_bf16(afB[kt], w2, cB2, 0, 0, 0);
        }
        const float bb1 = b1[ct * 16 + l15];
        const float bb2 = b2[ct * 16 + l15];
#pragma unroll
        for (int t = 0; t < 2; t++) {
            const f32x4 c1 = t ? cB1 : cA1;
            const f32x4 c2 = t ? cB2 : cA2;
#pragma unroll
            for (int r = 0; r < 4; r++) {
                const int row = row0 + t * 16 + quad * 4 + r;
                if (row < M) {
                    float v1 = c1[r] + bb1; v1 = v1 > 0.f ? v1 : 0.f;
                    float v2 = c2[r] + bb2; v2 = v2 > 0.f ? v2 : 0.f;
                    out1[(size_t)row * DIM + ct * 16 + l15] = v1;
                    out2[(size_t)row * DIM + ct * 16 + l15] = v2;
                }
            }
        }
    }
}

// ================= scans =================
// scan1: block-local exclusive scan of deg + dis = rsqrt(deg+1)
__global__ __launch_bounds__(256) void scan1_kernel(const int* __restrict__ deg,
                                                    int* __restrict__ offs,
                                                    int* __restrict__ bsum,
                                                    float* __restrict__ dis, int n) {
    __shared__ int sm[256];
    const int t = threadIdx.x, i = blockIdx.x * 256 + t;
    const int v = (i < n) ? deg[i] : 0;
    sm[t] = v;
    __syncthreads();
    for (int d = 1; d < 256; d <<= 1) {
        const int add = (t >= d) ? sm[t - d] : 0;
        __syncthreads();
        sm[t] += add;
        __syncthreads();
    }
    if (i < n) {
        offs[i] = sm[t] - v;
        dis[i]  = rsqrtf((float)v + 1.0f);
    }
    if (t == 255) bsum[blockIdx.x] = sm[255];
}

// scan23: apply block offsets; seed per-bucket cursors bcur[b] = offs[b*128]
__global__ __launch_bounds__(256) void scan23_kernel(int* __restrict__ offs,
                                                     const int* __restrict__ bsum,
                                                     int* __restrict__ bcur, int n) {
    __shared__ int sm[256];
    const int t = threadIdx.x, bid = blockIdx.x;
    int part = 0;
    for (int j = t; j < bid; j += 256) part += bsum[j];
    sm[t] = part;
    __syncthreads();
    for (int d = 128; d > 0; d >>= 1) {
        if (t < d) sm[t] += sm[t + d];
        __syncthreads();
    }
    const int boff = sm[0];
    const int i = bid * 256 + t;
    if (i < n) {
        const int o = offs[i] + boff;
        offs[i] = o;
        if ((i & 127) == 0) bcur[i >> 7] = o;   // bucket base cursor
    }
    if (bid == 0 && t == 0) offs[n] = EDGES;
}

// ================= phase A: bucketed write-combined edge scatter =================
// Replaces the random 8B scatter fill (R5/R6: 95us, 101.6MB partial-line
// writebacks, 1.6M global atomics). Each block: LDS histogram over 782
// dst-buckets -> LDS scan -> ONE global atomicAdd per (block,bucket) to
// reserve bucket-region space -> group records in LDS -> coalesced flush.
// Static LDS total: 32KB stage + 4x782x4B + 1KB = 45.5KB (< 64KB/block limit).
__global__ __launch_bounds__(256) void bucketA_kernel(
    const void* __restrict__ ei, int* __restrict__ bcur,
    int2* __restrict__ stage, int e_cnt)
{
    __shared__ int2 sstage[KA];                     // 32 KB
    __shared__ int hist[NB], lofs[NB], lcur[NB], gbase[NB];
    __shared__ int sm[256];
    const int m64 = wave_detect_m64(ei);
    const int t = threadIdx.x;
    const int base = blockIdx.x * KA;
    int cnt = e_cnt - base; cnt = cnt < KA ? cnt : KA;

    for (int i = t; i < NB; i += 256) hist[i] = 0;
    __syncthreads();

    // 1. histogram of dst buckets
    for (int j = t; j < cnt; j += 256) {
        const int d = load_idx(ei, (long long)EDGES + base + j, m64);
        atomicAdd(&hist[d >> 7], 1);
    }
    __syncthreads();

    // 2. exclusive scan hist -> lofs (4 entries/thread + block scan)
    const int i0 = t * 4;
    int h0 = (i0     < NB) ? hist[i0]     : 0;
    int h1 = (i0 + 1 < NB) ? hist[i0 + 1] : 0;
    int h2 = (i0 + 2 < NB) ? hist[i0 + 2] : 0;
    int h3 = (i0 + 3 < NB) ? hist[i0 + 3] : 0;
    const int psum = h0 + h1 + h2 + h3;
    sm[t] = psum;
    __syncthreads();
    for (int d = 1; d < 256; d <<= 1) {
        const int a = (t >= d) ? sm[t - d] : 0;
        __syncthreads();
        sm[t] += a;
        __syncthreads();
    }
    const int ex = sm[t] - psum;
    if (i0     < NB) { lofs[i0]     = ex;                lcur[i0]     = ex; }
    if (i0 + 1 < NB) { lofs[i0 + 1] = ex + h0;           lcur[i0 + 1] = ex + h0; }
    if (i0 + 2 < NB) { lofs[i0 + 2] = ex + h0 + h1;      lcur[i0 + 2] = ex + h0 + h1; }
    if (i0 + 3 < NB) { lofs[i0 + 3] = ex + h0 + h1 + h2; lcur[i0 + 3] = ex + h0 + h1 + h2; }
    __syncthreads();

    // 3. reserve global space per non-empty bucket
    for (int i = t; i < NB; i += 256)
        if (hist[i] > 0) gbase[i] = atomicAdd(&bcur[i], hist[i]);
    __syncthreads();

    // 4. group records {src,dst} in LDS by bucket
    for (int j = t; j < cnt; j += 256) {
        const int s = load_idx(ei, base + j, m64);
        const int d = load_idx(ei, (long long)EDGES + base + j, m64);
        const int p = atomicAdd(&lcur[d >> 7], 1);
        sstage[p] = make_int2(s, d);
    }
    __syncthreads();

    // 5. coalesced flush: record at LDS pos j belongs to bucket b with
    //    rank (j - lofs[b]) -> global gbase[b] + rank
    for (int j = t; j < cnt; j += 256) {
        const int2 r = sstage[j];
        const int b = r.y >> 7;
        stage[gbase[b] + (j - lofs[b])] = r;
    }
}

// ================= phase B: bucket-local counting sort + coef =================
// One block per bucket (128 nodes). Records land in the bucket's own ~16KB
// L2-resident range -> every line fully written by this block (no partial-line
// writeback amplification). coef computed here (dis complete).
__global__ __launch_bounds__(256) void bucketB_kernel(
    const int* __restrict__ offs, const float* __restrict__ dis,
    const int2* __restrict__ stage, int2* __restrict__ csr, int n)
{
    __shared__ int2 recs[3072];                 // 24 KB (~22.6 sigma above mean bucket size)
    __shared__ int lcur[128];
    const int t  = threadIdx.x;
    const int v0 = blockIdx.x << 7;
    int nv = n - v0; nv = nv < 128 ? nv : 128;
    const int base = offs[v0];
    const int cnt  = offs[v0 + nv] - base;
    if (t < nv) lcur[t] = offs[v0 + t] - base;
    const int lim = cnt < 3072 ? cnt : 3072;
    for (int j = t; j < lim; j += 256) recs[j] = stage[base + j];
    __syncthreads();
    for (int j = t; j < lim; j += 256) {
        const int2 r = recs[j];
        const int pos = atomicAdd(&lcur[r.y - v0], 1);
        const float cf = dis[r.x] * dis[r.y];
        csr[base + pos] = make_int2(r.x, __float_as_int(cf));
    }
    // overflow safety path (statistically unreachable; correct if hit)
    for (int j = 3072 + t; j < cnt; j += 256) {
        const int2 r = stage[base + j];
        const int pos = atomicAdd(&lcur[r.y - v0], 1);
        const float cf = dis[r.x] * dis[r.y];
        csr[base + pos] = make_int2(r.x, __float_as_int(cf));
    }
}

// ================= aggregate: depth-2 pipelined fp16 CSR gather =================
// (unchanged from R5/R6 — at the per-CU line-request floor, ~6.2 TB/s serviced)
template <int RELU, int WF32, int WBF16>
__global__ __launch_bounds__(256) void aggregate_kernel(
    const int* __restrict__ offs, const int2* __restrict__ csr,
    const float* __restrict__ dis, const _Float16* __restrict__ xw,
    const float* __restrict__ bias, float* __restrict__ out_f32,
    __bf16* __restrict__ out_bf, int n)
{
    __shared__ _Float16 sbuf[4][2][8 * DIM];     // 16 KB / block
    const int wid  = threadIdx.x >> 6;
    const int v    = blockIdx.x * 4 + wid;       // grid exact: v < n
    const int lane = threadIdx.x & 63;
    const int l15  = lane & 15;
    const int seg  = lane >> 4;                  // row-within-gather-instr
    const int lmod = lane & 7;

    const int beg = offs[v];
    const int deg = offs[v + 1] - beg;
    const int nb  = (deg + 7) >> 3;
    int lim = beg + deg - 1; if (lim < 0) lim = 0;   // clamp target

    _Float16* bufA = &sbuf[wid][0][0];
    _Float16* bufB = &sbuf[wid][1][0];

    f32x4 a0 = {0.f,0.f,0.f,0.f}, a1 = {0.f,0.f,0.f,0.f};
    if (seg == 0) {                              // self-loop term, one replica
        const float dv = dis[v];
        const float s2 = dv * dv;
        const f16x8 xv = *(const f16x8*)(xw + (size_t)v * DIM + l15 * 8);
#pragma unroll
        for (int j = 0; j < 4; j++) {
            a0[j] += s2 * (float)xv[j];
            a1[j] += s2 * (float)xv[j + 4];
        }
    }

    // rec loads on all lanes (8-way duplicated -> single 64B line)
    int p0 = beg + lmod;            p0 = p0 < lim ? p0 : lim;
    int2 rc = csr[p0];
#pragma unroll
    for (int g = 0; g < 2; g++) {                // issue gathers batch 0
        const int rs = __shfl(rc.x, g * 4 + seg);
        gather16(xw + (size_t)rs * DIM + l15 * 8, bufA + g * 512);
    }
    int p1 = beg + 8 + lmod;        p1 = p1 < lim ? p1 : lim;
    int2 rn1 = csr[p1];
    int p2 = beg + 16 + lmod;       p2 = p2 < lim ? p2 : lim;
    int2 rn2 = csr[p2];

    for (int b = 0; b < nb; ++b) {
        _Float16*       nbuf = (b & 1) ? bufA : bufB;
        const _Float16* cbuf = (b & 1) ? bufB : bufA;
        const bool more = (b + 1 < nb);          // wave-uniform
        int2 rn3 = rn2;

        if (more) {
            // issue gathers for batch b+1 (real edges only)
#pragma unroll
            for (int g = 0; g < 2; g++) {
                const int rs = __shfl(rn1.x, g * 4 + seg);
                gather16(xw + (size_t)rs * DIM + l15 * 8, nbuf + g * 512);
            }
            __builtin_amdgcn_sched_barrier(0);
            int p3 = beg + (b + 3) * 8 + lmod;  p3 = p3 < lim ? p3 : lim;
            rn3 = csr[p3];
            __builtin_amdgcn_sched_barrier(0);
            // FIFO: {gathers b+1 (2), rec (1)} may stay in flight => batch b landed
            asm volatile("s_waitcnt vmcnt(3)" ::: "memory");
            __builtin_amdgcn_sched_barrier(0);
        } else {
            asm volatile("s_waitcnt vmcnt(0)" ::: "memory");
            __builtin_amdgcn_sched_barrier(0);
        }

        const float cfy = __int_as_float(rc.y);
        const int rem = deg - b * 8;             // rows valid in this batch
#pragma unroll
        for (int s = 0; s < 2; s++) {
            const int r = s * 4 + seg;           // per-lane row 0..7
            const float cr = __shfl(cfy, r);
            if (r < rem) {
                const f16x8 hv = *(const f16x8*)(cbuf + s * 512 + lane * 8);
#pragma unroll
                for (int j = 0; j < 4; j++) {
                    a0[j] += cr * (float)hv[j];
                    a1[j] += cr * (float)hv[j + 4];
                }
            }
        }
        rc = rn1; rn1 = rn2; rn2 = rn3;
    }

    // reduce the 4 seg-partials; lanes 0..15 end up with cols l15*8..+7
#pragma unroll
    for (int j = 0; j < 4; j++) {
        a0[j] += __shfl_xor(a0[j], 16); a0[j] += __shfl_xor(a0[j], 32);
        a1[j] += __shfl_xor(a1[j], 16); a1[j] += __shfl_xor(a1[j], 32);
    }

    if (seg == 0) {
        const int cc = l15 * 8;
#pragma unroll
        for (int j = 0; j < 4; j++) { a0[j] += bias[cc + j]; a1[j] += bias[cc + 4 + j]; }
        if (RELU) {
#pragma unroll
            for (int j = 0; j < 4; j++) {
                a0[j] = a0[j] > 0.f ? a0[j] : 0.f;
                a1[j] = a1[j] > 0.f ? a1[j] : 0.f;
            }
        }
        if (WF32) {
            *(f32x4*)(out_f32 + (size_t)v * DIM + cc)     = a0;
            *(f32x4*)(out_f32 + (size_t)v * DIM + cc + 4) = a1;
        }
        if (WBF16) {
            bf16x8 bv;
#pragma unroll
            for (int j = 0; j < 4; j++) { bv[j] = (__bf16)a0[j]; bv[j + 4] = (__bf16)a1[j]; }
            *(bf16x8*)(out_bf + (size_t)v * DIM + cc) = bv;
        }
    }
    // safety drain (nb==0 path still has prologue gathers in flight at exit)
    asm volatile("s_waitcnt vmcnt(0)" ::: "memory");
}

// ================= launcher =================
extern "C" void kernel_launch(void* const* d_in, const int* in_sizes, int n_in,
                              void* d_out, int out_size, void* d_ws, size_t ws_size,
                              hipStream_t stream)
{
    const int N = NODES, E = EDGES;
    const size_t ND = (size_t)N * DIM;

    const float* x  = (const float*)d_in[0];
    const void*  ei = d_in[1];
    const float* W1 = (const float*)d_in[2];
    const float* b1 = (const float*)d_in[3];
    const float* W2 = (const float*)d_in[4];
    const float* b2 = (const float*)d_in[5];
    const float* Wv = (const float*)d_in[6];
    const float* bv = (const float*)d_in[7];
    const float* Wt = (const float*)d_in[8];
    const float* bt = (const float*)d_in[9];

    // ws layout (~14.4 MB)
    char* w = (char*)d_ws;
    float*  dis  = (float*)(w + 4096);          // 400 KB
    int*    offs = (int*)(w + 524288);          // 400 KB + 4
    int*    bsum = (int*)(w + 1048576);         // 1.6 KB
    int*    bcur = (int*)(w + 1056768);         // 3.2 KB (bucket cursors)
    int*    deg  = (int*)(w + 1064960);         // 400 KB (16B-aligned)
    int2*   csr  = (int2*)(w + 1507328);        // 12.8 MB
    __bf16* wf   = (__bf16*)(w + 14311424);     // 128 KB
    __bf16* wf1 = wf, *wf2 = wf + 16384, *wfv = wf + 32768, *wft = wf + 49152;

    float* out   = (float*)d_out;
    float* slot0 = out;              // phase-A staging (12.8MB) -> h (fp32, final)
    float* slot1 = out + ND;         // h1 (bf16, temp) -> vis (fp32, final)
    float* slot2 = out + 2 * ND;     // xw1/xw2 (fp16, temp) -> txt (fp32, final)
    __bf16*   h1bf  = (__bf16*)slot1;
    _Float16* xwh   = (_Float16*)slot2;
    int2*     stage = (int2*)slot0;  // dead until agg2 writes h

    const int GN   = (N + 255) / 256;   // 391
    const int GE   = (E + 255) / 256;   // 6250
    const int GM   = (N + 127) / 128;   // 782 (32 rows/wave)
    const int GAG  = (N + 3) / 4;       // 25000 (exact)
    const int GA   = (E + KA - 1) / KA; // 391
    const int GB   = NB;                // 782

    const int zcnt4 = N / 4;            // 25000 int4s to zero (deg)
    const int ZB    = (zcnt4 + 255) / 256;

    // 1. zero deg + prep weights
    init_kernel<<<ZB + 256, 256, 0, stream>>>(deg, zcnt4, ZB, W1, W2, Wv, Wt, wf);
    // 2. gemm1 fused with count_deg (independent workloads co-scheduled)
    gemm1_count_kernel<<<GM + GE, 256, 0, stream>>>(x, wf1, xwh, N, GM, ei, deg, E);
    // 3-4. scan (+dis), apply block offsets (+bucket cursors); offs[N]=E static
    scan1_kernel<<<GN, 256, 0, stream>>>(deg, offs, bsum, dis, N);
    scan23_kernel<<<GN, 256, 0, stream>>>(offs, bsum, bcur, N);
    // 5-6. bucketed CSR build (write-combined; replaces random-scatter fill)
    bucketA_kernel<<<GA, 256, 0, stream>>>(ei, bcur, stage, E);
    bucketB_kernel<<<GB, 256, 0, stream>>>(offs, dis, stage, csr, N);

    // ---- layer 1 ----
    aggregate_kernel<1, 0, 1><<<GAG, 256, 0, stream>>>(offs, csr, dis, xwh, b1,
                                                       nullptr, h1bf, N);
    // ---- layer 2 ----
    gemm128_kernel<0, 1, 1><<<GM, 256, 0, stream>>>(h1bf, wf2, nullptr, xwh, N);
    aggregate_kernel<0, 1, 0><<<GAG, 256, 0, stream>>>(offs, csr, dis, xwh, b2,
                                                       slot0, nullptr, N);
    // ---- heads (fused: read h once) ----
    gemm128_dual_kernel<<<GM, 256, 0, stream>>>(slot0, wfv, bv, wft, bt, slot1, slot2, N);
}

// Round 9
// 432.327 us; speedup vs baseline: 1.5393x; 1.1270x over previous
//
#include <hip/hip_runtime.h>
#include <hip/hip_bf16.h>
#include <hip/hip_fp16.h>

#define NODES 100000
#define EDGES 1600000
#define DIM   128
#define NB    782      // dst buckets: node >> 7 (128 nodes/bucket)
#define KA    4096     // edges per phase-A block (32KB LDS stage -> total ~45.5KB)
#define CAP   4096     // per-bucket fixed staging capacity (~45 sigma above mean 2046)

typedef __bf16   bf16x8 __attribute__((ext_vector_type(8)));
typedef float    f32x4  __attribute__((ext_vector_type(4)));
typedef _Float16 f16x8  __attribute__((ext_vector_type(8)));

// global_load_lds: per-lane GLOBAL src, wave-uniform LDS base + lane*16 dest.
__device__ __forceinline__ void gather16(const void* gp, void* lp) {
    __builtin_amdgcn_global_load_lds(
        (const __attribute__((address_space(1))) void*)gp,
        (__attribute__((address_space(3))) void*)lp, 16, 0, 0);
}

// ---- inline edge-index dtype detection (per wave) ----
// int64 indices < 2^31 => every odd dword zero. 64 random odd dwords all zero
// under int32: p ~ 0. L2-hot 256B read, 1 ballot.
__device__ __forceinline__ int wave_detect_m64(const void* ei) {
    const unsigned int* u = (const unsigned int*)ei;
    const unsigned long long nz = __ballot(u[2 * (threadIdx.x & 63) + 1] != 0);
    return (nz == 0ULL) ? 1 : 0;
}

__device__ __forceinline__ int load_idx(const void* ei, long long pos, int m64) {
    return m64 ? (int)((const long long*)ei)[pos] : ((const int*)ei)[pos];
}

// ================= init: seed bucket cursors + weight pre-pack =================
// bcur[b] = b*CAP (fixed staging regions; no dependency on degrees!), bcur[NB]=0
// is the overflow counter. prep layout: dest elem d: j=d&7, l15=(d>>3)&15,
// quad=(d>>7)&3, kt=(d>>9)&3, ct=(d>>11)&7;
// value = (bf16) W[(kt*32+quad*8+j)*128 + ct*16 + l15]
__global__ __launch_bounds__(256) void init_kernel(
    int* __restrict__ bcur,
    const float* __restrict__ Wa, const float* __restrict__ Wb,
    const float* __restrict__ Wc, const float* __restrict__ Wd,
    __bf16* __restrict__ wfout)
{
    const int bid = blockIdx.x;
    if (bid < 4) {
        const int i = bid * 256 + threadIdx.x;
        if (i < NB) bcur[i] = i * CAP;
        if (i == NB) bcur[NB] = 0;               // overflow counter
    } else {
        const int pb = bid - 4;                        // 0..255
        const int m  = pb >> 6;
        const int d  = (pb & 63) * 256 + threadIdx.x;  // 0..16383
        const float* W = (m == 0) ? Wa : (m == 1) ? Wb : (m == 2) ? Wc : Wd;
        const int j  = d & 7;
        const int l  = (d >> 3) & 15;
        const int q  = (d >> 7) & 3;
        const int kt = (d >> 9) & 3;
        const int ct = (d >> 11) & 7;
        wfout[m * 16384 + d] = (__bf16)W[(kt * 32 + q * 8 + j) * DIM + ct * 16 + l];
    }
}

// ================= GEMM body: [M x 128] @ prepacked bf16 W =================
// 32 rows per wave (two 16-row tiles share every Wf fragment load).
template <int RELU_BIAS, int ABF16, int OUTF16>
__device__ __forceinline__ void gemm_body(
    const void* __restrict__ Ain, const __bf16* __restrict__ Wf,
    const float* __restrict__ bias, void* __restrict__ outp, int M, int bid)
{
    const int wave = threadIdx.x >> 6;
    const int lane = threadIdx.x & 63;
    const int l15  = lane & 15;
    const int quad = lane >> 4;

    const int row0 = bid * 128 + wave * 32;
    if (row0 >= M) return;  // wave-uniform

    bf16x8 afA[4], afB[4];
#pragma unroll
    for (int t = 0; t < 2; t++) {
        const int arow  = row0 + t * 16 + l15;
        const int arowc = arow < M ? arow : (M - 1);
        bf16x8* af = t ? afB : afA;
        if (ABF16) {
            const __bf16* ap = (const __bf16*)Ain + (size_t)arowc * DIM + quad * 8;
#pragma unroll
            for (int kt = 0; kt < 4; kt++) af[kt] = *(const bf16x8*)(ap + kt * 32);
        } else {
            const float* ap = (const float*)Ain + (size_t)arowc * DIM + quad * 8;
#pragma unroll
            for (int kt = 0; kt < 4; kt++) {
                const f32x4 lo = *(const f32x4*)(ap + kt * 32);
                const f32x4 hi = *(const f32x4*)(ap + kt * 32 + 4);
                bf16x8 r;
#pragma unroll
                for (int j = 0; j < 4; j++) { r[j] = (__bf16)lo[j]; r[j + 4] = (__bf16)hi[j]; }
                af[kt] = r;
            }
        }
    }

#pragma unroll
    for (int ct = 0; ct < 8; ct++) {
        f32x4 cA = {0.f, 0.f, 0.f, 0.f};
        f32x4 cB = {0.f, 0.f, 0.f, 0.f};
#pragma unroll
        for (int kt = 0; kt < 4; kt++) {
            const bf16x8 b = *(const bf16x8*)(Wf + (ct * 4 + kt) * 512 + lane * 8);
            cA = __builtin_amdgcn_mfma_f32_16x16x32_bf16(afA[kt], b, cA, 0, 0, 0);
            cB = __builtin_amdgcn_mfma_f32_16x16x32_bf16(afB[kt], b, cB, 0, 0, 0);
        }
        const float bb = RELU_BIAS ? bias[ct * 16 + l15] : 0.f;
#pragma unroll
        for (int t = 0; t < 2; t++) {
            const f32x4 c = t ? cB : cA;
#pragma unroll
            for (int r = 0; r < 4; r++) {
                const int row = row0 + t * 16 + quad * 4 + r;
                if (row < M) {
                    float v = c[r];
                    if (RELU_BIAS) { v += bb; v = v > 0.f ? v : 0.f; }
                    const size_t idx = (size_t)row * DIM + ct * 16 + l15;
                    if (OUTF16) ((_Float16*)outp)[idx] = (_Float16)v;
                    else        ((float*)outp)[idx]    = v;
                }
            }
        }
    }
}

template <int RELU_BIAS, int ABF16, int OUTF16>
__global__ __launch_bounds__(256) void gemm128_kernel(
    const void* __restrict__ Ain, const __bf16* __restrict__ Wf,
    const float* __restrict__ bias, void* __restrict__ outp, int M)
{
    gemm_body<RELU_BIAS, ABF16, OUTF16>(Ain, Wf, bias, outp, M, blockIdx.x);
}

// ---- fused: gemm1 (x@W1 -> fp16) on blocks [0,gm) + bucketA on blocks [gm,gm+GA) ----
// bucketA: write-combined edge staging into FIXED per-bucket regions (no offs
// dependency -> co-schedulable with gemm1). Per block: LDS histogram over 782
// dst-buckets -> LDS scan -> one global atomicAdd per (block,bucket) reserving
// region space -> group {src,dst} in LDS -> coalesced flush. Overflow beyond a
// bucket's CAP spills to a global list (novf = bcur[NB]); statistically empty.
__global__ __launch_bounds__(256) void gemm1_bucketA_kernel(
    const float* __restrict__ x, const __bf16* __restrict__ wf1,
    _Float16* __restrict__ xwh, int M, int gm,
    const void* __restrict__ ei, int* __restrict__ bcur,
    int2* __restrict__ stage, int2* __restrict__ ovf, int e_cnt)
{
    __shared__ int2 sstage[KA];                     // 32 KB
    __shared__ int hist[NB], lofs[NB], lcur[NB], gbase[NB];
    __shared__ int sm[256];

    const int bid = blockIdx.x;
    if (bid < gm) {
        gemm_body<0, 0, 1>(x, wf1, nullptr, xwh, M, bid);
        return;
    }

    const int m64 = wave_detect_m64(ei);
    const int t = threadIdx.x;
    const int base = (bid - gm) * KA;
    int cnt = e_cnt - base; cnt = cnt < KA ? cnt : KA;
    if (cnt <= 0) return;

    for (int i = t; i < NB; i += 256) hist[i] = 0;
    __syncthreads();

    // 1. histogram of dst buckets
    for (int j = t; j < cnt; j += 256) {
        const int d = load_idx(ei, (long long)EDGES + base + j, m64);
        atomicAdd(&hist[d >> 7], 1);
    }
    __syncthreads();

    // 2. exclusive scan hist -> lofs (4 entries/thread + block scan)
    const int i0 = t * 4;
    int h0 = (i0     < NB) ? hist[i0]     : 0;
    int h1 = (i0 + 1 < NB) ? hist[i0 + 1] : 0;
    int h2 = (i0 + 2 < NB) ? hist[i0 + 2] : 0;
    int h3 = (i0 + 3 < NB) ? hist[i0 + 3] : 0;
    const int psum = h0 + h1 + h2 + h3;
    sm[t] = psum;
    __syncthreads();
    for (int d = 1; d < 256; d <<= 1) {
        const int a = (t >= d) ? sm[t - d] : 0;
        __syncthreads();
        sm[t] += a;
        __syncthreads();
    }
    const int ex = sm[t] - psum;
    if (i0     < NB) { lofs[i0]     = ex;                lcur[i0]     = ex; }
    if (i0 + 1 < NB) { lofs[i0 + 1] = ex + h0;           lcur[i0 + 1] = ex + h0; }
    if (i0 + 2 < NB) { lofs[i0 + 2] = ex + h0 + h1;      lcur[i0 + 2] = ex + h0 + h1; }
    if (i0 + 3 < NB) { lofs[i0 + 3] = ex + h0 + h1 + h2; lcur[i0 + 3] = ex + h0 + h1 + h2; }
    __syncthreads();

    // 3. reserve region space per non-empty bucket
    for (int i = t; i < NB; i += 256)
        if (hist[i] > 0) gbase[i] = atomicAdd(&bcur[i], hist[i]);
    __syncthreads();

    // 4. group records {src,dst} in LDS by bucket
    for (int j = t; j < cnt; j += 256) {
        const int s = load_idx(ei, base + j, m64);
        const int d = load_idx(ei, (long long)EDGES + base + j, m64);
        const int p = atomicAdd(&lcur[d >> 7], 1);
        sstage[p] = make_int2(s, d);
    }
    __syncthreads();

    // 5. coalesced flush: record at LDS pos j belongs to bucket b with rank
    //    (j - lofs[b]); positions past the bucket's CAP spill to overflow list.
    for (int j = t; j < cnt; j += 256) {
        const int2 r = sstage[j];
        const int b = r.y >> 7;
        const int p = gbase[b] + (j - lofs[b]);
        if (p < (b + 1) * CAP) stage[p] = r;
        else                   ovf[atomicAdd(&bcur[NB], 1)] = r;
    }
}

// Dual-weight head GEMM, 32 rows/wave.
__global__ __launch_bounds__(256) void gemm128_dual_kernel(
    const float* __restrict__ A,
    const __bf16* __restrict__ Wf1, const float* __restrict__ b1,
    const __bf16* __restrict__ Wf2, const float* __restrict__ b2,
    float* __restrict__ out1, float* __restrict__ out2, int M)
{
    const int wave = threadIdx.x >> 6;
    const int lane = threadIdx.x & 63;
    const int l15  = lane & 15;
    const int quad = lane >> 4;

    const int row0 = blockIdx.x * 128 + wave * 32;
    if (row0 >= M) return;

    bf16x8 afA[4], afB[4];
#pragma unroll
    for (int t = 0; t < 2; t++) {
        const int arow  = row0 + t * 16 + l15;
        const int arowc = arow < M ? arow : (M - 1);
        const float* ap = A + (size_t)arowc * DIM + quad * 8;
        bf16x8* af = t ? afB : afA;
#pragma unroll
        for (int kt = 0; kt < 4; kt++) {
            const f32x4 lo = *(const f32x4*)(ap + kt * 32);
            const f32x4 hi = *(const f32x4*)(ap + kt * 32 + 4);
            bf16x8 r;
#pragma unroll
            for (int j = 0; j < 4; j++) { r[j] = (__bf16)lo[j]; r[j + 4] = (__bf16)hi[j]; }
            af[kt] = r;
        }
    }

#pragma unroll
    for (int ct = 0; ct < 8; ct++) {
        f32x4 cA1 = {0.f,0.f,0.f,0.f}, cA2 = {0.f,0.f,0.f,0.f};
        f32x4 cB1 = {0.f,0.f,0.f,0.f}, cB2 = {0.f,0.f,0.f,0.f};
#pragma unroll
        for (int kt = 0; kt < 4; kt++) {
            const bf16x8 w1 = *(const bf16x8*)(Wf1 + (ct * 4 + kt) * 512 + lane * 8);
            const bf16x8 w2 = *(const bf16x8*)(Wf2 + (ct * 4 + kt) * 512 + lane * 8);
            cA1 = __builtin_amdgcn_mfma_f32_16x16x32_bf16(afA[kt], w1, cA1, 0, 0, 0);
            cA2 = __builtin_amdgcn_mfma_f32_16x16x32_bf16(afA[kt], w2, cA2, 0, 0, 0);
            cB1 = __builtin_amdgcn_mfma_f32_16x16x32_bf16(afB[kt], w1, cB1, 0, 0, 0);
            cB2 = __builtin_amdgcn_mfma_f32_16x16x32_bf16(afB[kt], w2, cB2, 0, 0, 0);
        }
        const float bb1 = b1[ct * 16 + l15];
        const float bb2 = b2[ct * 16 + l15];
#pragma unroll
        for (int t = 0; t < 2; t++) {
            const f32x4 c1 = t ? cB1 : cA1;
            const f32x4 c2 = t ? cB2 : cA2;
#pragma unroll
            for (int r = 0; r < 4; r++) {
                const int row = row0 + t * 16 + quad * 4 + r;
                if (row < M) {
                    float v1 = c1[r] + bb1; v1 = v1 > 0.f ? v1 : 0.f;
                    float v2 = c2[r] + bb2; v2 = v2 > 0.f ? v2 : 0.f;
                    out1[(size_t)row * DIM + ct * 16 + l15] = v1;
                    out2[(size_t)row * DIM + ct * 16 + l15] = v2;
                }
            }
        }
    }
}

// ================= bucketB1: degrees via LDS atomics (replaces count_deg) ========
// One block per bucket: histogram its staged records' dst (LDS, 128 counters),
// write deg coalesced. Zero global atomics (was 1.6M device-scope).
__global__ __launch_bounds__(256) void bucketB1_kernel(
    const int* __restrict__ bcur, const int2* __restrict__ ovf,
    const int2* __restrict__ stage, int* __restrict__ deg, int n)
{
    __shared__ int ldeg[128];
    const int t = threadIdx.x, b = blockIdx.x;
    const int v0 = b << 7;
    if (t < 128) ldeg[t] = 0;
    __syncthreads();
    int cnt = bcur[b] - b * CAP; cnt = cnt < CAP ? cnt : CAP;
    const int2* reg = stage + (size_t)b * CAP;
    for (int j = t; j < cnt; j += 256) atomicAdd(&ldeg[reg[j].y & 127], 1);
    const int no = bcur[NB];
    for (int j = t; j < no; j += 256) {
        const int2 r = ovf[j];
        if ((r.y >> 7) == b) atomicAdd(&ldeg[r.y & 127], 1);
    }
    __syncthreads();
    const int v = v0 + t;
    if (t < 128 && v < n) deg[v] = ldeg[t];
}

// ================= scans =================
// scan1: block-local exclusive scan of deg + dis = rsqrt(deg+1)
__global__ __launch_bounds__(256) void scan1_kernel(const int* __restrict__ deg,
                                                    int* __restrict__ offs,
                                                    int* __restrict__ bsum,
                                                    float* __restrict__ dis, int n) {
    __shared__ int sm[256];
    const int t = threadIdx.x, i = blockIdx.x * 256 + t;
    const int v = (i < n) ? deg[i] : 0;
    sm[t] = v;
    __syncthreads();
    for (int d = 1; d < 256; d <<= 1) {
        const int add = (t >= d) ? sm[t - d] : 0;
        __syncthreads();
        sm[t] += add;
        __syncthreads();
    }
    if (i < n) {
        offs[i] = sm[t] - v;
        dis[i]  = rsqrtf((float)v + 1.0f);
    }
    if (t == 255) bsum[blockIdx.x] = sm[255];
}

// scan23: apply block offsets (each block sums bsum[j<bid] itself, L2-hot)
__global__ __launch_bounds__(256) void scan23_kernel(int* __restrict__ offs,
                                                     const int* __restrict__ bsum, int n) {
    __shared__ int sm[256];
    const int t = threadIdx.x, bid = blockIdx.x;
    int part = 0;
    for (int j = t; j < bid; j += 256) part += bsum[j];
    sm[t] = part;
    __syncthreads();
    for (int d = 128; d > 0; d >>= 1) {
        if (t < d) sm[t] += sm[t + d];
        __syncthreads();
    }
    const int boff = sm[0];
    const int i = bid * 256 + t;
    if (i < n) offs[i] += boff;
    if (bid == 0 && t == 0) offs[n] = EDGES;
}

// ================= bucketB2: bucket-local counting sort + coef =================
// One block per bucket; reads its own ~16-32KB L2-resident region, LDS cursors
// (absolute), writes final {src, coef} records into csr. Write-combined: every
// csr line is fully produced by this block.
__global__ __launch_bounds__(256) void bucketB2_kernel(
    const int* __restrict__ offs, const float* __restrict__ dis,
    const int* __restrict__ bcur, const int2* __restrict__ ovf,
    const int2* __restrict__ stage, int2* __restrict__ csr, int n)
{
    __shared__ int lcur[128];
    const int t = threadIdx.x, b = blockIdx.x;
    const int v0 = b << 7;
    int nv = n - v0; nv = nv < 128 ? nv : 128;
    if (t < nv) lcur[t] = offs[v0 + t];
    __syncthreads();
    int cnt = bcur[b] - b * CAP; cnt = cnt < CAP ? cnt : CAP;
    const int2* reg = stage + (size_t)b * CAP;
    for (int j = t; j < cnt; j += 256) {
        const int2 r = reg[j];
        const int pos = atomicAdd(&lcur[r.y & 127], 1);
        csr[pos] = make_int2(r.x, __float_as_int(dis[r.x] * dis[r.y]));
    }
    const int no = bcur[NB];
    for (int j = t; j < no; j += 256) {
        const int2 r = ovf[j];
        if ((r.y >> 7) == b) {
            const int pos = atomicAdd(&lcur[r.y & 127], 1);
            csr[pos] = make_int2(r.x, __float_as_int(dis[r.x] * dis[r.y]));
        }
    }
}

// ================= aggregate: depth-2 pipelined fp16 CSR gather =================
// (unchanged — at the per-CU line-request floor, ~6.2 TB/s serviced)
template <int RELU, int WF32, int WBF16>
__global__ __launch_bounds__(256) void aggregate_kernel(
    const int* __restrict__ offs, const int2* __restrict__ csr,
    const float* __restrict__ dis, const _Float16* __restrict__ xw,
    const float* __restrict__ bias, float* __restrict__ out_f32,
    __bf16* __restrict__ out_bf, int n)
{
    __shared__ _Float16 sbuf[4][2][8 * DIM];     // 16 KB / block
    const int wid  = threadIdx.x >> 6;
    const int v    = blockIdx.x * 4 + wid;       // grid exact: v < n
    const int lane = threadIdx.x & 63;
    const int l15  = lane & 15;
    const int seg  = lane >> 4;                  // row-within-gather-instr
    const int lmod = lane & 7;

    const int beg = offs[v];
    const int deg = offs[v + 1] - beg;
    const int nb  = (deg + 7) >> 3;
    int lim = beg + deg - 1; if (lim < 0) lim = 0;   // clamp target

    _Float16* bufA = &sbuf[wid][0][0];
    _Float16* bufB = &sbuf[wid][1][0];

    f32x4 a0 = {0.f,0.f,0.f,0.f}, a1 = {0.f,0.f,0.f,0.f};
    if (seg == 0) {                              // self-loop term, one replica
        const float dv = dis[v];
        const float s2 = dv * dv;
        const f16x8 xv = *(const f16x8*)(xw + (size_t)v * DIM + l15 * 8);
#pragma unroll
        for (int j = 0; j < 4; j++) {
            a0[j] += s2 * (float)xv[j];
            a1[j] += s2 * (float)xv[j + 4];
        }
    }

    // rec loads on all lanes (8-way duplicated -> single 64B line)
    int p0 = beg + lmod;            p0 = p0 < lim ? p0 : lim;
    int2 rc = csr[p0];
#pragma unroll
    for (int g = 0; g < 2; g++) {                // issue gathers batch 0
        const int rs = __shfl(rc.x, g * 4 + seg);
        gather16(xw + (size_t)rs * DIM + l15 * 8, bufA + g * 512);
    }
    int p1 = beg + 8 + lmod;        p1 = p1 < lim ? p1 : lim;
    int2 rn1 = csr[p1];
    int p2 = beg + 16 + lmod;       p2 = p2 < lim ? p2 : lim;
    int2 rn2 = csr[p2];

    for (int b = 0; b < nb; ++b) {
        _Float16*       nbuf = (b & 1) ? bufA : bufB;
        const _Float16* cbuf = (b & 1) ? bufB : bufA;
        const bool more = (b + 1 < nb);          // wave-uniform
        int2 rn3 = rn2;

        if (more) {
            // issue gathers for batch b+1 (real edges only)
#pragma unroll
            for (int g = 0; g < 2; g++) {
                const int rs = __shfl(rn1.x, g * 4 + seg);
                gather16(xw + (size_t)rs * DIM + l15 * 8, nbuf + g * 512);
            }
            __builtin_amdgcn_sched_barrier(0);
            int p3 = beg + (b + 3) * 8 + lmod;  p3 = p3 < lim ? p3 : lim;
            rn3 = csr[p3];
            __builtin_amdgcn_sched_barrier(0);
            // FIFO: {gathers b+1 (2), rec (1)} may stay in flight => batch b landed
            asm volatile("s_waitcnt vmcnt(3)" ::: "memory");
            __builtin_amdgcn_sched_barrier(0);
        } else {
            asm volatile("s_waitcnt vmcnt(0)" ::: "memory");
            __builtin_amdgcn_sched_barrier(0);
        }

        const float cfy = __int_as_float(rc.y);
        const int rem = deg - b * 8;             // rows valid in this batch
#pragma unroll
        for (int s = 0; s < 2; s++) {
            const int r = s * 4 + seg;           // per-lane row 0..7
            const float cr = __shfl(cfy, r);
            if (r < rem) {
                const f16x8 hv = *(const f16x8*)(cbuf + s * 512 + lane * 8);
#pragma unroll
                for (int j = 0; j < 4; j++) {
                    a0[j] += cr * (float)hv[j];
                    a1[j] += cr * (float)hv[j + 4];
                }
            }
        }
        rc = rn1; rn1 = rn2; rn2 = rn3;
    }

    // reduce the 4 seg-partials; lanes 0..15 end up with cols l15*8..+7
#pragma unroll
    for (int j = 0; j < 4; j++) {
        a0[j] += __shfl_xor(a0[j], 16); a0[j] += __shfl_xor(a0[j], 32);
        a1[j] += __shfl_xor(a1[j], 16); a1[j] += __shfl_xor(a1[j], 32);
    }

    if (seg == 0) {
        const int cc = l15 * 8;
#pragma unroll
        for (int j = 0; j < 4; j++) { a0[j] += bias[cc + j]; a1[j] += bias[cc + 4 + j]; }
        if (RELU) {
#pragma unroll
            for (int j = 0; j < 4; j++) {
                a0[j] = a0[j] > 0.f ? a0[j] : 0.f;
                a1[j] = a1[j] > 0.f ? a1[j] : 0.f;
            }
        }
        if (WF32) {
            *(f32x4*)(out_f32 + (size_t)v * DIM + cc)     = a0;
            *(f32x4*)(out_f32 + (size_t)v * DIM + cc + 4) = a1;
        }
        if (WBF16) {
            bf16x8 bv;
#pragma unroll
            for (int j = 0; j < 4; j++) { bv[j] = (__bf16)a0[j]; bv[j + 4] = (__bf16)a1[j]; }
            *(bf16x8*)(out_bf + (size_t)v * DIM + cc) = bv;
        }
    }
    // safety drain (nb==0 path still has prologue gathers in flight at exit)
    asm volatile("s_waitcnt vmcnt(0)" ::: "memory");
}

// ================= launcher =================
extern "C" void kernel_launch(void* const* d_in, const int* in_sizes, int n_in,
                              void* d_out, int out_size, void* d_ws, size_t ws_size,
                              hipStream_t stream)
{
    const int N = NODES, E = EDGES;
    const size_t ND = (size_t)N * DIM;

    const float* x  = (const float*)d_in[0];
    const void*  ei = d_in[1];
    const float* W1 = (const float*)d_in[2];
    const float* b1 = (const float*)d_in[3];
    const float* W2 = (const float*)d_in[4];
    const float* b2 = (const float*)d_in[5];
    const float* Wv = (const float*)d_in[6];
    const float* bv = (const float*)d_in[7];
    const float* Wt = (const float*)d_in[8];
    const float* bt = (const float*)d_in[9];

    // ws layout (~14.4 MB)
    char* w = (char*)d_ws;
    float*  dis  = (float*)(w + 4096);          // 400 KB
    int*    offs = (int*)(w + 524288);          // 400 KB + 4
    int*    bsum = (int*)(w + 1048576);         // 1.6 KB
    int*    bcur = (int*)(w + 1056768);         // NB+1 ints (cursors + ovf count)
    int*    deg  = (int*)(w + 1064960);         // 400 KB
    int2*   csr  = (int2*)(w + 1507328);        // 12.8 MB
    __bf16* wf   = (__bf16*)(w + 14311424);     // 128 KB
    __bf16* wf1 = wf, *wf2 = wf + 16384, *wfv = wf + 32768, *wft = wf + 49152;

    float* out   = (float*)d_out;
    float* slot0 = out;              // bucket staging (25.6MB) -> h (fp32, final)
    float* slot1 = out + ND;         // ovf list -> h1 (bf16, temp) -> vis (fp32, final)
    float* slot2 = out + 2 * ND;     // xw1/xw2 (fp16, temp) -> txt (fp32, final)
    __bf16*   h1bf  = (__bf16*)slot1;
    _Float16* xwh   = (_Float16*)slot2;
    int2*     stage = (int2*)slot0;  // NB*CAP*8B = 25.6MB; slot0 dead until agg2
    int2*     ovf   = (int2*)slot1;  // overflow list; dead before agg1 writes h1

    const int GN   = (N + 255) / 256;   // 391
    const int GM   = (N + 127) / 128;   // 782 (32 rows/wave)
    const int GAG  = (N + 3) / 4;       // 25000 (exact)
    const int GA   = (E + KA - 1) / KA; // 391
    const int GB   = NB;                // 782

    // 1. seed bucket cursors + prep weights
    init_kernel<<<4 + 256, 256, 0, stream>>>(bcur, W1, W2, Wv, Wt, wf);
    // 2. gemm1 co-scheduled with bucketA edge staging (both input-only deps)
    gemm1_bucketA_kernel<<<GM + GA, 256, 0, stream>>>(x, wf1, xwh, N, GM,
                                                      ei, bcur, stage, ovf, E);
    // 3. degrees from staged buckets (LDS atomics only)
    bucketB1_kernel<<<GB, 256, 0, stream>>>(bcur, ovf, stage, deg, N);
    // 4-5. scan (+dis), apply block offsets
    scan1_kernel<<<GN, 256, 0, stream>>>(deg, offs, bsum, dis, N);
    scan23_kernel<<<GN, 256, 0, stream>>>(offs, bsum, N);
    // 6. bucket-local counting sort -> final CSR (+coef)
    bucketB2_kernel<<<GB, 256, 0, stream>>>(offs, dis, bcur, ovf, stage, csr, N);

    // ---- layer 1 ----
    aggregate_kernel<1, 0, 1><<<GAG, 256, 0, stream>>>(offs, csr, dis, xwh, b1,
                                                       nullptr, h1bf, N);
    // ---- layer 2 ----
    gemm128_kernel<0, 1, 1><<<GM, 256, 0, stream>>>(h1bf, wf2, nullptr, xwh, N);
    aggregate_kernel<0, 1, 0><<<GAG, 256, 0, stream>>>(offs, csr, dis, xwh, b2,
                                                       slot0, nullptr, N);
    // ---- heads (fused: read h once) ----
    gemm128_dual_kernel<<<GM, 256, 0, stream>>>(slot0, wfv, bv, wft, bt, slot1, slot2, N);
}